// Round 4
// baseline (577.349 us; speedup 1.0000x reference)
//
#include <hip/hip_runtime.h>
#include <math.h>

static constexpr float EPS_F = 1.1920929e-07f;           // finfo(float32).eps
static constexpr float SCL   = 0.044194173824159216f;    // 1/sqrt(512)

typedef __attribute__((ext_vector_type(8))) short  short8;   // 8 bf16 (4 VGPRs)
typedef __attribute__((ext_vector_type(4))) float  floatx4;  // MFMA C/D

__device__ __forceinline__ float4 ld4(const float* p){ return *(const float4*)p; }
__device__ __forceinline__ ushort f2bf(float f){
  union { float f; unsigned u; } v; v.f = f;
  return (ushort)((v.u + 0x7FFFu + ((v.u >> 16) & 1u)) >> 16);   // RNE
}
__device__ __forceinline__ float bf2f(ushort h){
  union { unsigned u; float f; } v; v.u = ((unsigned)h) << 16;
  return v.f;
}
#define MFMA16(A,B,C) __builtin_amdgcn_mfma_f32_16x16x32_bf16((A),(B),(C),0,0,0)

// async global->LDS, 16B/lane. LDS dst = wave-uniform base + lane*16.
__device__ __forceinline__ void gld16(void* lds, const void* g){
  __builtin_amdgcn_global_load_lds(
      (const __attribute__((address_space(1))) unsigned int*)g,
      (__attribute__((address_space(3))) unsigned int*)lds, 16, 0, 0);
}

// ===========================================================================
// Corrected swizzle (R3): rows are 64B (32 bf16). 2-bit chunk key, no row-bit
// spill: element (row R, 8-elem chunk c) at LDS elem off R*32 + 8*(c ^ ((R>>1)&3)).
//   Frag read (row base16+l15, chunk quad): off = R*32 + (quad*8 ^ ((l15>>1)&3)*8)
//   -> granule-set = 4*(l15&1) + (quad ^ ((l15>>1)&3)): bijective over 8
//   consecutive lanes (same class as the measured-zero-conflict 128B-row swizzle).
//   Staging (linear gld dst, 1024B/wave-op = 16 rows): lane L -> row base+(L>>2),
//   chunk (L&3)^((L>>3)&3).  (bijective; verified against read contract)
// ===========================================================================

// ---------------------------------------------------------------------------
// prep: merged cvt(q,k) + transpose(x) + transpose(W1) + transpose(W2).
// ---------------------------------------------------------------------------
__global__ __launch_bounds__(256)
void prep(const float* __restrict__ q, const float* __restrict__ k,
          const float* __restrict__ x, const float* __restrict__ W1,
          const float* __restrict__ W2,
          ushort* __restrict__ Qb, ushort* __restrict__ Kb,
          ushort* __restrict__ XT, ushort* __restrict__ W1T,
          ushort* __restrict__ W2T)
{
  const int bi = blockIdx.x, t = threadIdx.x;
  if (bi < 8192){
    const size_t i4 = ((size_t)bi*256 + t)*4;
    float4 v = ld4(q + i4);
    ushort4 o;
    o.x=f2bf(v.x*SCL); o.y=f2bf(v.y*SCL); o.z=f2bf(v.z*SCL); o.w=f2bf(v.w*SCL);
    *(ushort4*)(Qb + i4) = o;
    float4 u = ld4(k + i4);
    o.x=f2bf(u.x); o.y=f2bf(u.y); o.z=f2bf(u.z); o.w=f2bf(u.w);
    *(ushort4*)(Kb + i4) = o;
    return;
  }
  const float* in; ushort* out; int R, C, c0, r0; size_t boff;
  if (bi < 10240){
    const int id = bi - 8192;
    in = x; out = XT; R = 2048; C = 512;
    boff = (size_t)(id >> 8) * R * C;
    c0 = (id & 7)*64; r0 = ((id >> 3) & 31)*64;
  } else if (bi < 10368){
    const int id = bi - 10240;
    in = W1; out = W1T; R = 512; C = 1024; boff = 0;
    c0 = (id & 15)*64; r0 = (id >> 4)*64;
  } else {
    const int id = bi - 10368;
    in = W2; out = W2T; R = 512; C = 512; boff = 0;
    c0 = (id & 7)*64; r0 = (id >> 3)*64;
  }
  __shared__ __align__(16) ushort tile[64*68];
#pragma unroll
  for (int it = 0; it < 4; ++it){
    int f = t + it*256, r = f >> 4, c4 = f & 15;
    float4 v = ld4(in + boff + (size_t)(r0+r)*C + c0 + c4*4);
    ushort4 o; o.x=f2bf(v.x); o.y=f2bf(v.y); o.z=f2bf(v.z); o.w=f2bf(v.w);
    *(ushort4*)&tile[r*68 + c4*4] = o;
  }
  __syncthreads();
#pragma unroll
  for (int it = 0; it < 4; ++it){
    int f = t + it*256, c = f >> 4, q4 = f & 15;
    ushort4 o;
    o.x = tile[(q4*4+0)*68 + c];
    o.y = tile[(q4*4+1)*68 + c];
    o.z = tile[(q4*4+2)*68 + c];
    o.w = tile[(q4*4+3)*68 + c];
    *(ushort4*)(out + boff + (size_t)(c0+c)*R + r0 + q4*4) = o;
  }
}

// ---------------------------------------------------------------------------
// qk3: E = exp(Q*SCL @ K^T) (bf16) + per-row sums (atomic).
// 256x256 tile, BK=32, 8 waves (2M x 4N, wave 128x64), 64KB LDS dbuf ->
// 2 blocks/CU; grid 512 = ALL blocks resident. 2-phase counted-vmcnt:
// stage A(kt+1)@p0 -> buf^1, B(kt+2)@p1 -> cur (B read-done after p0 BAR);
// end-of-tile vmcnt(2) (keeps B(kt+2) in flight), 0 only at tail.
// b=id&7: one batch per XCD (Q+K 4MB L2-resident).
// ---------------------------------------------------------------------------
__global__ __launch_bounds__(512, 4)
void qk3(const ushort* __restrict__ Qbf, const ushort* __restrict__ Kbf,
         ushort* __restrict__ scores, float* __restrict__ rowsum)
{
  extern __shared__ __align__(16) ushort smem[];  // A 2x8192 | B 2x8192 elems
  const int t = threadIdx.x, lane = t & 63, w = t >> 6;
  const int id = blockIdx.x;
  const int b = id & 7, s = id >> 3;               // s 0..63
  const int m0 = (s & 7) * 256, n0 = (s >> 3) * 256;
  const ushort* Ab = Qbf + ((size_t)b*2048 + m0)*512;
  const ushort* Bb = Kbf + ((size_t)b*2048 + n0)*512;
  const int wr = w >> 2, wc = w & 3;               // wave tile 128m x 64n
  const int l15 = lane & 15, quad = lane >> 4;
  const int swk = ((l15 >> 1) & 3) * 8;            // 2-bit chunk key
  const int rl  = lane >> 2;                       // staging row-in-16
  const int cl  = (lane & 3) ^ ((lane >> 3) & 3);  // staging chunk
  const int aofb = (wr*128 + l15)*32 + (quad*8 ^ swk);   // + mf*512
  const int bofb = (wc*64  + l15)*32 + (quad*8 ^ swk);   // + n*512

  floatx4 acc[8][4];
#pragma unroll
  for (int i = 0; i < 8; ++i)
#pragma unroll
    for (int j = 0; j < 4; ++j) acc[i][j] = (floatx4){0.f,0.f,0.f,0.f};

  // stage one 256x32 tile (A or B), K-tile kt: 2 wave-ops (32 rows/wave).
  auto stage = [&](int dstE, const ushort* gsrc, int kt){
#pragma unroll
    for (int r = 0; r < 2; ++r)
      gld16(smem + dstE + w*1024 + r*512,
            gsrc + (size_t)(w*32 + r*16 + rl)*512 + kt*32 + cl*8);
  };

  const int NT = 16;                               // K/BK = 512/32
  // prologue: A0(2), B0(2), B1(2) -> keep B1 in flight
  stage(0,             Ab, 0);
  stage(16384,         Bb, 0);
  stage(16384 + 8192,  Bb, 1);
  asm volatile("s_waitcnt vmcnt(2)" ::: "memory");
  __builtin_amdgcn_s_barrier();

  short8 af[4], bfr[4];
  for (int kt = 0; kt < NT; ++kt){
    const int cur = kt & 1;
    const ushort* A  = smem + cur*8192;
    const ushort* Bt = smem + 16384 + cur*8192;
    // ---- phase 0: B all + A mf0-3; stage A(kt+1) -> buf^1
#pragma unroll
    for (int n = 0; n < 4; ++n) bfr[n] = *(const short8*)&Bt[bofb + n*512];
#pragma unroll
    for (int m = 0; m < 4; ++m) af[m]  = *(const short8*)&A[aofb + m*512];
    if (kt+1 < NT) stage((cur^1)*8192, Ab, kt+1);
    __builtin_amdgcn_s_barrier();
    asm volatile("s_waitcnt lgkmcnt(0)" ::: "memory");
    __builtin_amdgcn_sched_barrier(0);
    __builtin_amdgcn_s_setprio(1);
#pragma unroll
    for (int m = 0; m < 4; ++m)
#pragma unroll
      for (int n = 0; n < 4; ++n)
        acc[m][n] = MFMA16(af[m], bfr[n], acc[m][n]);
    __builtin_amdgcn_s_setprio(0);
    __builtin_amdgcn_s_barrier();
    // ---- phase 1: A mf4-7; stage B(kt+2) -> cur (read-done after p0 BAR)
#pragma unroll
    for (int m = 0; m < 4; ++m) af[m] = *(const short8*)&A[aofb + (4+m)*512];
    if (kt+2 < NT) stage(16384 + cur*8192, Bb, kt+2);
    __builtin_amdgcn_s_barrier();
    asm volatile("s_waitcnt lgkmcnt(0)" ::: "memory");
    __builtin_amdgcn_sched_barrier(0);
    __builtin_amdgcn_s_setprio(1);
#pragma unroll
    for (int m = 0; m < 4; ++m)
#pragma unroll
      for (int n = 0; n < 4; ++n)
        acc[4+m][n] = MFMA16(af[m], bfr[n], acc[4+m][n]);
    __builtin_amdgcn_s_setprio(0);
    if (kt + 2 < NT) asm volatile("s_waitcnt vmcnt(2)" ::: "memory");
    else             asm volatile("s_waitcnt vmcnt(0)" ::: "memory");
    __builtin_amdgcn_s_barrier();
  }

  // epilogue: e = exp(s) (no max-sub: |s| <~ 6), bf16 store, rowsum atomics
  ushort* sb = scores + (size_t)b*2048*2048;
#pragma unroll
  for (int m = 0; m < 8; ++m){
    const int rm = m0 + wr*128 + m*16 + quad*4;
    float rs[4] = {0.f,0.f,0.f,0.f};
#pragma unroll
    for (int n = 0; n < 4; ++n){
      const int cn = n0 + wc*64 + n*16 + l15;
#pragma unroll
      for (int r = 0; r < 4; ++r){
        float e = __expf(acc[m][n][r]);
        ushort eb = f2bf(e);
        sb[(size_t)(rm + r)*2048 + cn] = eb;
        rs[r] += bf2f(eb);
      }
    }
#pragma unroll
    for (int r = 0; r < 4; ++r){
      float p2 = rs[r];
      p2 += __shfl_xor(p2, 1); p2 += __shfl_xor(p2, 2);
      p2 += __shfl_xor(p2, 4); p2 += __shfl_xor(p2, 8);
      if (l15 == 0)
        atomicAdd(&rowsum[(size_t)b*2048 + rm + r], p2);
    }
  }
}

// ---------------------------------------------------------------------------
// pv8: attn = (E @ X) / l. 256x128, BK=64, 8 waves, 96KB dbuf, counted vmcnt.
// (unchanged -- best measured performer, 0 conflicts)
// ---------------------------------------------------------------------------
__global__ __launch_bounds__(512)
void pv8(const ushort* __restrict__ P, const ushort* __restrict__ XT,
         const float* __restrict__ rowsum, ushort* __restrict__ attn)
{
  extern __shared__ __align__(16) ushort smem[];   // [2 bufs][A 16384 | B 8192]
  const int t = threadIdx.x, lane = t & 63, w = t >> 6;
  const int id = blockIdx.x;
  const int b = id & 7, s = id >> 3;
  const int m0 = (s >> 2) * 256;
  const int n0 = (s & 3) * 128;
  const ushort* Pb = P  + ((size_t)b*2048 + m0)*2048;
  const ushort* Xb = XT + ((size_t)b*512  + n0)*2048;
  const int wr = w >> 1, wc = w & 1;
  const int l15 = lane & 15, quad = lane >> 4;
  const int c0  = (quad ^ (l15 & 7)) * 8;
  const int srow = lane >> 3;
  const int skc  = ((lane & 7) ^ srow) * 8;

  floatx4 acc[4][4];
#pragma unroll
  for (int i = 0; i < 4; ++i)
#pragma unroll
    for (int j = 0; j < 4; ++j) acc[i][j] = (floatx4){0.f,0.f,0.f,0.f};

  auto stageA = [&](int buf, int kt, int h){
    ushort* base = smem + buf*24576 + h*8192;
#pragma unroll
    for (int r = 0; r < 2; ++r){
      const int rw = r*8 + w;
      gld16(base + rw*512,
            Pb + (size_t)(h*128 + rw*8 + srow)*2048 + kt*64 + skc);
    }
  };
  auto stageB = [&](int buf, int kt){
    ushort* base = smem + buf*24576 + 16384;
#pragma unroll
    for (int r = 0; r < 2; ++r){
      const int rw = r*8 + w;
      gld16(base + rw*512,
            Xb + (size_t)(rw*8 + srow)*2048 + kt*64 + skc);
    }
  };

  stageA(0, 0, 0);
  stageA(0, 0, 1);
  stageB(0, 0);
  stageB(1, 1);
  asm volatile("s_waitcnt vmcnt(2)" ::: "memory");
  __builtin_amdgcn_s_barrier();

  short8 af[2][2], bfr[4][2];
  const int NT = 32;

  for (int kt = 0; kt < NT; ++kt){
    const int cur = kt & 1;
    const ushort* A  = smem + cur*24576;
    const ushort* Bt = A + 16384;

#pragma unroll
    for (int ni = 0; ni < 4; ++ni)
#pragma unroll
      for (int ks = 0; ks < 2; ++ks)
        bfr[ni][ks] = *(const short8*)
          &Bt[(wc*64 + ni*16 + l15)*64 + (c0 ^ (ks*32))];
#pragma unroll
    for (int mi = 0; mi < 2; ++mi)
#pragma unroll
      for (int ks = 0; ks < 2; ++ks)
        af[mi][ks] = *(const short8*)
          &A[(wr*64 + mi*16 + l15)*64 + (c0 ^ (ks*32))];
    if (kt+1 < NT) stageA(cur^1, kt+1, 0);
    __builtin_amdgcn_s_barrier();
    asm volatile("s_waitcnt lgkmcnt(0)" ::: "memory");
    __builtin_amdgcn_sched_barrier(0);
    __builtin_amdgcn_s_setprio(1);
#pragma unroll
    for (int mi = 0; mi < 2; ++mi)
#pragma unroll
      for (int ni = 0; ni < 4; ++ni)
#pragma unroll
        for (int ks = 0; ks < 2; ++ks)
          acc[mi][ni] = MFMA16(af[mi][ks], bfr[ni][ks], acc[mi][ni]);
    __builtin_amdgcn_s_setprio(0);
    __builtin_amdgcn_s_barrier();

#pragma unroll
    for (int mi = 0; mi < 2; ++mi)
#pragma unroll
      for (int ks = 0; ks < 2; ++ks)
        af[mi][ks] = *(const short8*)
          &A[(wr*64 + (2+mi)*16 + l15)*64 + (c0 ^ (ks*32))];
    if (kt+1 < NT) stageA(cur^1, kt+1, 1);
    if (kt+2 < NT) stageB(cur, kt+2);
    __builtin_amdgcn_s_barrier();
    asm volatile("s_waitcnt lgkmcnt(0)" ::: "memory");
    __builtin_amdgcn_sched_barrier(0);
    __builtin_amdgcn_s_setprio(1);
#pragma unroll
    for (int mi = 0; mi < 2; ++mi)
#pragma unroll
      for (int ni = 0; ni < 4; ++ni)
#pragma unroll
        for (int ks = 0; ks < 2; ++ks)
          acc[2+mi][ni] = MFMA16(af[mi][ks], bfr[ni][ks], acc[2+mi][ni]);
    __builtin_amdgcn_s_setprio(0);
    if (kt + 2 < NT) asm volatile("s_waitcnt vmcnt(2)" ::: "memory");
    else             asm volatile("s_waitcnt vmcnt(0)" ::: "memory");
    __builtin_amdgcn_s_barrier();
  }

  ushort* ab = attn + (size_t)b*2048*512;
#pragma unroll
  for (int m = 0; m < 4; ++m){
    const int rm = m0 + wr*64 + m*16 + quad*4;
    float inv[4];
#pragma unroll
    for (int r = 0; r < 4; ++r)
      inv[r] = 1.0f / rowsum[(size_t)b*2048 + rm + r];
#pragma unroll
    for (int n = 0; n < 4; ++n){
      const int cn = n0 + wc*64 + n*16 + l15;
#pragma unroll
      for (int r = 0; r < 4; ++r)
        ab[(size_t)(rm + r)*512 + cn] = f2bf(acc[m][n][r] * inv[r]);
    }
  }
}

// ---------------------------------------------------------------------------
// res_rms1: h = rmsnorm(x + attn)*n1w -> bf16 in-place over attn buffer.
// ---------------------------------------------------------------------------
__global__ __launch_bounds__(256)
void res_rms1(const float* __restrict__ x, const float* __restrict__ n1w,
              ushort* __restrict__ ah)
{
  const int wid = threadIdx.x >> 6, lane = threadIdx.x & 63;
  const size_t row = (size_t)blockIdx.x*4 + wid;
  ushort* ar = ah + row*512;
  const float* xr = x + row*512;
  ushort4 a0 = *(const ushort4*)&ar[lane*8];
  ushort4 a1 = *(const ushort4*)&ar[lane*8 + 4];
  float4 x0 = ld4(xr + lane*8), x1 = ld4(xr + lane*8 + 4);
  float h[8];
  h[0]=x0.x+bf2f(a0.x); h[1]=x0.y+bf2f(a0.y); h[2]=x0.z+bf2f(a0.z); h[3]=x0.w+bf2f(a0.w);
  h[4]=x1.x+bf2f(a1.x); h[5]=x1.y+bf2f(a1.y); h[6]=x1.z+bf2f(a1.z); h[7]=x1.w+bf2f(a1.w);
  float ss = 0.f;
#pragma unroll
  for (int e=0;e<8;++e) ss += h[e]*h[e];
#pragma unroll
  for (int s=1;s<64;s<<=1) ss += __shfl_xor(ss, s);
  const float rr = rsqrtf(ss*(1.0f/512.0f) + EPS_F);
  ushort4 o0, o1;
  o0.x=f2bf(h[0]*rr*n1w[lane*8+0]); o0.y=f2bf(h[1]*rr*n1w[lane*8+1]);
  o0.z=f2bf(h[2]*rr*n1w[lane*8+2]); o0.w=f2bf(h[3]*rr*n1w[lane*8+3]);
  o1.x=f2bf(h[4]*rr*n1w[lane*8+4]); o1.y=f2bf(h[5]*rr*n1w[lane*8+5]);
  o1.z=f2bf(h[6]*rr*n1w[lane*8+6]); o1.w=f2bf(h[7]*rr*n1w[lane*8+7]);
  *(ushort4*)&ar[lane*8]     = o0;
  *(ushort4*)&ar[lane*8 + 4] = o1;
}

// ---------------------------------------------------------------------------
// ffn2: proj = hbf @ W1 + b1 (W1T), g = gelu(x1)*x2. 256x128 template,
// corrected 2-bit swizzle key. grid 512.
// ---------------------------------------------------------------------------
__global__ __launch_bounds__(512, 4)
void ffn2(const ushort* __restrict__ hbf, const ushort* __restrict__ W1T,
          const float* __restrict__ b1, ushort* __restrict__ gbuf)
{
  extern __shared__ __align__(16) ushort smem[];
  const int t = threadIdx.x, lane = t & 63, w = t >> 6;
  const int id = blockIdx.x;
  const int xcd = id & 7, sl = id >> 3;            // sl 0..63
  const int m0 = (xcd*8 + (sl >> 3)) * 256;
  const int n0 = (sl & 7) * 64;
  const ushort* Ab = hbf + (size_t)m0*512;
  const int wr = w >> 1, wc = w & 1;
  const int l15 = lane & 15, quad = lane >> 4;
  const int rl = lane >> 2;
  const int cl = (lane & 3) ^ ((lane >> 3) & 3);
  const int sw = ((l15 >> 1) & 3) * 8;
  int aoff[4], boff[4];
#pragma unroll
  for (int m = 0; m < 4; ++m)
    aoff[m] = ((wr*64 + m*16 + l15)*32 + quad*8) ^ sw;
#pragma unroll
  for (int n = 0; n < 4; ++n)
    boff[n] = ((wc*64 + n*16 + l15)*32 + quad*8) ^ sw;
  const size_t aS0 = (size_t)(w*16 + rl)*512 + cl*8;
  const size_t aS1 = aS0 + (size_t)128*512;
  const int br = w*16 + rl;                        // B tile row 0..127
  const int bgrow = ((br >> 5) & 1)*512 + n0 + (br >> 6)*32 + (br & 31);
  const size_t bS0 = (size_t)bgrow*512 + cl*8;
  const int aD = w*512, bD = 16384 + w*512;

  floatx4 acc[4][4];
#pragma unroll
  for (int i = 0; i < 4; ++i)
#pragma unroll
    for (int j = 0; j < 4; ++j) acc[i][j] = (floatx4){0.f,0.f,0.f,0.f};

  const int NT = 16;
  gld16(smem + aD,        Ab + aS0);
  gld16(smem + 4096 + aD, Ab + aS1);
  gld16(smem + bD,        W1T + bS0);
  gld16(smem + 4096 + bD, W1T + bS0 + 32);
  asm volatile("s_waitcnt vmcnt(1)" ::: "memory");
  __builtin_amdgcn_s_barrier();

  short8 af[2], bfr[4];
  for (int kt = 0; kt < NT; ++kt){
    const int cur = kt & 1;
    const ushort* A  = smem + cur*8192;
    const ushort* Bt = smem + 16384 + cur*4096;
#pragma unroll
    for (int n = 0; n < 4; ++n) bfr[n] = *(const short8*)&Bt[boff[n]];
#pragma unroll
    for (int m = 0; m < 2; ++m) af[m] = *(const short8*)&A[aoff[m]];
    if (kt+1 < NT){
      ushort* d = smem + (cur^1)*8192;
      const size_t ko = (size_t)(kt+1)*32;
      gld16(d + aD,        Ab + aS0 + ko);
      gld16(d + 4096 + aD, Ab + aS1 + ko);
    }
    __builtin_amdgcn_s_barrier();
    asm volatile("s_waitcnt lgkmcnt(0)" ::: "memory");
    __builtin_amdgcn_sched_barrier(0);
    __builtin_amdgcn_s_setprio(1);
#pragma unroll
    for (int m = 0; m < 2; ++m)
#pragma unroll
      for (int n = 0; n < 4; ++n)
        acc[m][n] = MFMA16(af[m], bfr[n], acc[m][n]);
    __builtin_amdgcn_s_setprio(0);
    __builtin_amdgcn_s_barrier();
#pragma unroll
    for (int m = 0; m < 2; ++m) af[m] = *(const short8*)&A[aoff[2+m]];
    if (kt+2 < NT)
      gld16(smem + cur*4096 + bD, W1T + bS0 + (size_t)(kt+2)*32);
    __builtin_amdgcn_s_barrier();
    asm volatile("s_waitcnt lgkmcnt(0)" ::: "memory");
    __builtin_amdgcn_sched_barrier(0);
    __builtin_amdgcn_s_setprio(1);
#pragma unroll
    for (int m = 0; m < 2; ++m)
#pragma unroll
      for (int n = 0; n < 4; ++n)
        acc[2+m][n] = MFMA16(af[m], bfr[n], acc[2+m][n]);
    __builtin_amdgcn_s_setprio(0);
    if (kt + 2 < NT) asm volatile("s_waitcnt vmcnt(1)" ::: "memory");
    else             asm volatile("s_waitcnt vmcnt(0)" ::: "memory");
    __builtin_amdgcn_s_barrier();
  }

#pragma unroll
  for (int m = 0; m < 4; ++m){
#pragma unroll
    for (int n = 0; n < 2; ++n){
      const int col = n0 + wc*32 + n*16 + l15;
      const float bb1 = b1[col], bb2 = b1[512 + col];
#pragma unroll
      for (int r = 0; r < 4; ++r){
        const int row = m0 + wr*64 + m*16 + quad*4 + r;
        float x1 = acc[m][n][r]     + bb1;
        float x2 = acc[m][n+2][r]   + bb2;
        float gl = 0.5f*x1*(1.0f + erff(x1*0.70710678118654752f));
        gbuf[(size_t)row*512 + col] = f2bf(gl*x2);
      }
    }
  }
}

// ---------------------------------------------------------------------------
// ff2: ff = g @ W2 (via W2T). 256x128 template, corrected swizzle. grid 256.
// ---------------------------------------------------------------------------
__global__ __launch_bounds__(512, 4)
void ff2(const ushort* __restrict__ gb, const ushort* __restrict__ W2T,
         ushort* __restrict__ ff)
{
  extern __shared__ __align__(16) ushort smem[];
  const int t = threadIdx.x, lane = t & 63, w = t >> 6;
  const int id = blockIdx.x;
  const int xcd = id & 7, sl = id >> 3;            // sl 0..31
  const int m0 = (xcd*8 + (sl >> 2)) * 256;
  const int n0 = (sl & 3) * 128;
  const ushort* Ab = gb  + (size_t)m0*512;
  const ushort* Bb = W2T + (size_t)n0*512;
  const int wr = w >> 1, wc = w & 1;
  const int l15 = lane & 15, quad = lane >> 4;
  const int rl = lane >> 2;
  const int cl = (lane & 3) ^ ((lane >> 3) & 3);
  const int sw = ((l15 >> 1) & 3) * 8;
  int aoff[4], boff[4];
#pragma unroll
  for (int m = 0; m < 4; ++m)
    aoff[m] = ((wr*64 + m*16 + l15)*32 + quad*8) ^ sw;
#pragma unroll
  for (int n = 0; n < 4; ++n)
    boff[n] = ((wc*64 + n*16 + l15)*32 + quad*8) ^ sw;
  const size_t aS0 = (size_t)(w*16 + rl)*512 + cl*8;
  const size_t aS1 = aS0 + (size_t)128*512;
  const size_t bS0 = (size_t)(w*16 + rl)*512 + cl*8;
  const int aD = w*512, bD = 16384 + w*512;

  floatx4 acc[4][4];
#pragma unroll
  for (int i = 0; i < 4; ++i)
#pragma unroll
    for (int j = 0; j < 4; ++j) acc[i][j] = (floatx4){0.f,0.f,0.f,0.f};

  const int NT = 16;
  gld16(smem + aD,        Ab + aS0);
  gld16(smem + 4096 + aD, Ab + aS1);
  gld16(smem + bD,        Bb + bS0);
  gld16(smem + 4096 + bD, Bb + bS0 + 32);
  asm volatile("s_waitcnt vmcnt(1)" ::: "memory");
  __builtin_amdgcn_s_barrier();

  short8 af[2], bfr[4];
  for (int kt = 0; kt < NT; ++kt){
    const int cur = kt & 1;
    const ushort* A  = smem + cur*8192;
    const ushort* Bt = smem + 16384 + cur*4096;
#pragma unroll
    for (int n = 0; n < 4; ++n) bfr[n] = *(const short8*)&Bt[boff[n]];
#pragma unroll
    for (int m = 0; m < 2; ++m) af[m] = *(const short8*)&A[aoff[m]];
    if (kt+1 < NT){
      ushort* d = smem + (cur^1)*8192;
      const size_t ko = (size_t)(kt+1)*32;
      gld16(d + aD,        Ab + aS0 + ko);
      gld16(d + 4096 + aD, Ab + aS1 + ko);
    }
    __builtin_amdgcn_s_barrier();
    asm volatile("s_waitcnt lgkmcnt(0)" ::: "memory");
    __builtin_amdgcn_sched_barrier(0);
    __builtin_amdgcn_s_setprio(1);
#pragma unroll
    for (int m = 0; m < 2; ++m)
#pragma unroll
      for (int n = 0; n < 4; ++n)
        acc[m][n] = MFMA16(af[m], bfr[n], acc[m][n]);
    __builtin_amdgcn_s_setprio(0);
    __builtin_amdgcn_s_barrier();
#pragma unroll
    for (int m = 0; m < 2; ++m) af[m] = *(const short8*)&A[aoff[2+m]];
    if (kt+2 < NT)
      gld16(smem + cur*4096 + bD, Bb + bS0 + (size_t)(kt+2)*32);
    __builtin_amdgcn_s_barrier();
    asm volatile("s_waitcnt lgkmcnt(0)" ::: "memory");
    __builtin_amdgcn_sched_barrier(0);
    __builtin_amdgcn_s_setprio(1);
#pragma unroll
    for (int m = 0; m < 2; ++m)
#pragma unroll
      for (int n = 0; n < 4; ++n)
        acc[2+m][n] = MFMA16(af[m], bfr[n], acc[2+m][n]);
    __builtin_amdgcn_s_setprio(0);
    if (kt + 2 < NT) asm volatile("s_waitcnt vmcnt(1)" ::: "memory");
    else             asm volatile("s_waitcnt vmcnt(0)" ::: "memory");
    __builtin_amdgcn_s_barrier();
  }

#pragma unroll
  for (int m = 0; m < 4; ++m){
    const int rm = m0 + wr*64 + m*16 + quad*4;
#pragma unroll
    for (int n = 0; n < 4; ++n){
      const int cn = n0 + wc*64 + n*16 + l15;
#pragma unroll
      for (int r = 0; r < 4; ++r)
        ff[(size_t)(rm + r)*512 + cn] = f2bf(acc[m][n][r]);
    }
  }
}

// ---------------------------------------------------------------------------
// res_rms2: y = h + ff + b2; out = rmsnorm(y)*n2w (fp32). One wave per row.
// ---------------------------------------------------------------------------
__global__ __launch_bounds__(256)
void res_rms2(const ushort* __restrict__ hbf, const ushort* __restrict__ ff,
              const float* __restrict__ b2, const float* __restrict__ n2w,
              float* __restrict__ out)
{
  const int wid = threadIdx.x >> 6, lane = threadIdx.x & 63;
  const size_t row = (size_t)blockIdx.x*4 + wid;
  const ushort* hr = hbf + row*512;
  const ushort* fr = ff  + row*512;
  ushort4 h0 = *(const ushort4*)&hr[lane*8];
  ushort4 h1 = *(const ushort4*)&hr[lane*8 + 4];
  ushort4 f0 = *(const ushort4*)&fr[lane*8];
  ushort4 f1 = *(const ushort4*)&fr[lane*8 + 4];
  float4 bb0 = ld4(b2 + lane*8), bb1 = ld4(b2 + lane*8 + 4);
  float y[8];
  y[0]=bf2f(h0.x)+bf2f(f0.x)+bb0.x; y[1]=bf2f(h0.y)+bf2f(f0.y)+bb0.y;
  y[2]=bf2f(h0.z)+bf2f(f0.z)+bb0.z; y[3]=bf2f(h0.w)+bf2f(f0.w)+bb0.w;
  y[4]=bf2f(h1.x)+bf2f(f1.x)+bb1.x; y[5]=bf2f(h1.y)+bf2f(f1.y)+bb1.y;
  y[6]=bf2f(h1.z)+bf2f(f1.z)+bb1.z; y[7]=bf2f(h1.w)+bf2f(f1.w)+bb1.w;
  float ss = 0.f;
#pragma unroll
  for (int e=0;e<8;++e) ss += y[e]*y[e];
#pragma unroll
  for (int s=1;s<64;s<<=1) ss += __shfl_xor(ss, s);
  const float rr = rsqrtf(ss*(1.0f/512.0f) + EPS_F);
  float4 w0 = ld4(n2w + lane*8), w1 = ld4(n2w + lane*8 + 4);
  float* orow = out + row*512;
  float4 o0, o1;
  o0.x=y[0]*rr*w0.x; o0.y=y[1]*rr*w0.y; o0.z=y[2]*rr*w0.z; o0.w=y[3]*rr*w0.w;
  o1.x=y[4]*rr*w1.x; o1.y=y[5]*rr*w1.y; o1.z=y[6]*rr*w1.z; o1.w=y[7]*rr*w1.w;
  *(float4*)(orow + lane*8)     = o0;
  *(float4*)(orow + lane*8 + 4) = o1;
}

// ---------------------------------------------------------------------------
extern "C" void kernel_launch(void* const* d_in, const int* in_sizes, int n_in,
                              void* d_out, int out_size, void* d_ws, size_t ws_size,
                              hipStream_t stream)
{
  const float* x   = (const float*)d_in[0];
  const float* q   = (const float*)d_in[1];
  const float* k   = (const float*)d_in[2];
  const float* W1  = (const float*)d_in[3];
  const float* b1  = (const float*)d_in[4];
  const float* W2  = (const float*)d_in[5];
  const float* b2  = (const float*)d_in[6];
  const float* n1w = (const float*)d_in[7];
  const float* n2w = (const float*)d_in[8];
  float* out = (float*)d_out;

  // ws (ushort units): scores 64MB | XT 16MB | Qbf 16MB | Kbf 16MB
  //                    | W1T 1MB | W2T .5MB | rowsum 64KB(float)
  ushort* scoresP = (ushort*)d_ws;
  ushort* XT  = scoresP + (size_t)8*2048*2048;
  ushort* Qbf = XT  + (size_t)8*512*2048;
  ushort* Kbf = Qbf + (size_t)8*2048*512;
  ushort* W1T = Kbf + (size_t)8*2048*512;
  ushort* W2T = W1T + (size_t)1024*512;
  float*  rowsum = (float*)(W2T + (size_t)512*512);
  ushort* attn = Qbf;      // alias: Qbf dead after qk3
  ushort* hbf  = Qbf;      // res_rms1 rewrites attn in place
  ushort* gbuf = Kbf;      // alias: Kbf dead after qk3
  ushort* ffb  = scoresP;  // alias: scores dead after pv8

  hipMemsetAsync(rowsum, 0, (size_t)8*2048*sizeof(float), stream);
  prep     <<<dim3(10432),  256, 0, stream>>>(q, k, x, W1, W2, Qbf, Kbf, XT, W1T, W2T);
  qk3      <<<dim3(512),    512, 65536, stream>>>(Qbf, Kbf, scoresP, rowsum);
  pv8      <<<dim3(256),    512, 98304, stream>>>(scoresP, XT, rowsum, attn);
  res_rms1 <<<dim3(4096),   256, 0, stream>>>(x, n1w, hbf);
  ffn2     <<<dim3(512),    512, 49152, stream>>>(hbf, W1T, b1, gbuf);
  ff2      <<<dim3(256),    512, 49152, stream>>>(gbuf, W2T, ffb);
  res_rms2 <<<dim3(4096),   256, 0, stream>>>(hbf, ffb, b2, n2w, out);
}

// Round 5
// 302.817 us; speedup vs baseline: 1.9066x; 1.9066x over previous
//
#include <hip/hip_runtime.h>
#include <math.h>

static constexpr float EPS_F = 1.1920929e-07f;           // finfo(float32).eps
static constexpr float SCL   = 0.044194173824159216f;    // 1/sqrt(512)

typedef __attribute__((ext_vector_type(8))) short  short8;   // 8 bf16 (4 VGPRs)
typedef __attribute__((ext_vector_type(4))) float  floatx4;  // MFMA C/D

__device__ __forceinline__ float4 ld4(const float* p){ return *(const float4*)p; }
__device__ __forceinline__ ushort f2bf(float f){
  union { float f; unsigned u; } v; v.f = f;
  return (ushort)((v.u + 0x7FFFu + ((v.u >> 16) & 1u)) >> 16);   // RNE
}
__device__ __forceinline__ float bf2f(ushort h){
  union { unsigned u; float f; } v; v.u = ((unsigned)h) << 16;
  return v.f;
}
#define MFMA16(A,B,C) __builtin_amdgcn_mfma_f32_16x16x32_bf16((A),(B),(C),0,0,0)

// async global->LDS, 16B/lane. LDS dst = wave-uniform base + lane*16.
__device__ __forceinline__ void gld16(void* lds, const void* g){
  __builtin_amdgcn_global_load_lds(
      (const __attribute__((address_space(1))) unsigned int*)g,
      (__attribute__((address_space(3))) unsigned int*)lds, 16, 0, 0);
}

// ===========================================================================
// Swizzle (R3, verified-correct): rows are 64B (32 bf16). 2-bit chunk key:
// element (row R, 8-elem chunk c) at LDS elem off R*32 + 8*(c ^ ((R>>1)&3)).
// Staging (linear gld dst): lane L -> row base+(L>>2), chunk (L&3)^((L>>3)&3).
// REGISTER RULE (R4 lesson): 8-wave 256^2 tile needs 128 acc regs/thread ->
// total ~200-250 unified regs. NEVER force >2 waves/SIMD via launch_bounds:
// (512,4) capped budget at 128 and spilled acc to scratch (1.5 GB HBM, 6x slow).
// ===========================================================================

// ---------------------------------------------------------------------------
// prep: merged cvt(q,k) + transpose(x) + transpose(W1) + transpose(W2).
// ---------------------------------------------------------------------------
__global__ __launch_bounds__(256)
void prep(const float* __restrict__ q, const float* __restrict__ k,
          const float* __restrict__ x, const float* __restrict__ W1,
          const float* __restrict__ W2,
          ushort* __restrict__ Qb, ushort* __restrict__ Kb,
          ushort* __restrict__ XT, ushort* __restrict__ W1T,
          ushort* __restrict__ W2T)
{
  const int bi = blockIdx.x, t = threadIdx.x;
  if (bi < 8192){
    const size_t i4 = ((size_t)bi*256 + t)*4;
    float4 v = ld4(q + i4);
    ushort4 o;
    o.x=f2bf(v.x*SCL); o.y=f2bf(v.y*SCL); o.z=f2bf(v.z*SCL); o.w=f2bf(v.w*SCL);
    *(ushort4*)(Qb + i4) = o;
    float4 u = ld4(k + i4);
    o.x=f2bf(u.x); o.y=f2bf(u.y); o.z=f2bf(u.z); o.w=f2bf(u.w);
    *(ushort4*)(Kb + i4) = o;
    return;
  }
  const float* in; ushort* out; int R, C, c0, r0; size_t boff;
  if (bi < 10240){
    const int id = bi - 8192;
    in = x; out = XT; R = 2048; C = 512;
    boff = (size_t)(id >> 8) * R * C;
    c0 = (id & 7)*64; r0 = ((id >> 3) & 31)*64;
  } else if (bi < 10368){
    const int id = bi - 10240;
    in = W1; out = W1T; R = 512; C = 1024; boff = 0;
    c0 = (id & 15)*64; r0 = (id >> 4)*64;
  } else {
    const int id = bi - 10368;
    in = W2; out = W2T; R = 512; C = 512; boff = 0;
    c0 = (id & 7)*64; r0 = (id >> 3)*64;
  }
  __shared__ __align__(16) ushort tile[64*68];
#pragma unroll
  for (int it = 0; it < 4; ++it){
    int f = t + it*256, r = f >> 4, c4 = f & 15;
    float4 v = ld4(in + boff + (size_t)(r0+r)*C + c0 + c4*4);
    ushort4 o; o.x=f2bf(v.x); o.y=f2bf(v.y); o.z=f2bf(v.z); o.w=f2bf(v.w);
    *(ushort4*)&tile[r*68 + c4*4] = o;
  }
  __syncthreads();
#pragma unroll
  for (int it = 0; it < 4; ++it){
    int f = t + it*256, c = f >> 4, q4 = f & 15;
    ushort4 o;
    o.x = tile[(q4*4+0)*68 + c];
    o.y = tile[(q4*4+1)*68 + c];
    o.z = tile[(q4*4+2)*68 + c];
    o.w = tile[(q4*4+3)*68 + c];
    *(ushort4*)(out + boff + (size_t)(c0+c)*R + r0 + q4*4) = o;
  }
}

// ---------------------------------------------------------------------------
// qk3: E = exp(Q*SCL @ K^T) (bf16) + per-row sums (atomic).
// 256x256 tile, BK=32, 8 waves (2M x 4N, wave 128x64), 64KB LDS dbuf.
// __launch_bounds__(512): FULL reg budget (acc 128 + operands ~ 200-250
// unified regs, 2 waves/SIMD = m201's proven operating point). grid 512.
// 2-phase counted-vmcnt: stage A(kt+1)@p0 -> buf^1, B(kt+2)@p1 -> cur;
// end-of-tile vmcnt(2), 0 only at tail. b=id&7: one batch per XCD.
// ---------------------------------------------------------------------------
__global__ __launch_bounds__(512)
void qk3(const ushort* __restrict__ Qbf, const ushort* __restrict__ Kbf,
         ushort* __restrict__ scores, float* __restrict__ rowsum)
{
  extern __shared__ __align__(16) ushort smem[];  // A 2x8192 | B 2x8192 elems
  const int t = threadIdx.x, lane = t & 63, w = t >> 6;
  const int id = blockIdx.x;
  const int b = id & 7, s = id >> 3;               // s 0..63
  const int m0 = (s & 7) * 256, n0 = (s >> 3) * 256;
  const ushort* Ab = Qbf + ((size_t)b*2048 + m0)*512;
  const ushort* Bb = Kbf + ((size_t)b*2048 + n0)*512;
  const int wr = w >> 2, wc = w & 3;               // wave tile 128m x 64n
  const int l15 = lane & 15, quad = lane >> 4;
  const int swk = ((l15 >> 1) & 3) * 8;            // 2-bit chunk key
  const int rl  = lane >> 2;                       // staging row-in-16
  const int cl  = (lane & 3) ^ ((lane >> 3) & 3);  // staging chunk
  const int aofb = (wr*128 + l15)*32 + (quad*8 ^ swk);   // + mf*512
  const int bofb = (wc*64  + l15)*32 + (quad*8 ^ swk);   // + n*512

  floatx4 acc[8][4];
#pragma unroll
  for (int i = 0; i < 8; ++i)
#pragma unroll
    for (int j = 0; j < 4; ++j) acc[i][j] = (floatx4){0.f,0.f,0.f,0.f};

  // stage one 256x32 tile (A or B), K-tile kt: 2 wave-ops (32 rows/wave).
  auto stage = [&](int dstE, const ushort* gsrc, int kt){
#pragma unroll
    for (int r = 0; r < 2; ++r)
      gld16(smem + dstE + w*1024 + r*512,
            gsrc + (size_t)(w*32 + r*16 + rl)*512 + kt*32 + cl*8);
  };

  const int NT = 16;                               // K/BK = 512/32
  // prologue: A0(2), B0(2), B1(2) -> keep B1 in flight
  stage(0,             Ab, 0);
  stage(16384,         Bb, 0);
  stage(16384 + 8192,  Bb, 1);
  asm volatile("s_waitcnt vmcnt(2)" ::: "memory");
  __builtin_amdgcn_s_barrier();

  short8 af[4], bfr[4];
  for (int kt = 0; kt < NT; ++kt){
    const int cur = kt & 1;
    const ushort* A  = smem + cur*8192;
    const ushort* Bt = smem + 16384 + cur*8192;
    // ---- phase 0: B all + A mf0-3; stage A(kt+1) -> buf^1
#pragma unroll
    for (int n = 0; n < 4; ++n) bfr[n] = *(const short8*)&Bt[bofb + n*512];
#pragma unroll
    for (int m = 0; m < 4; ++m) af[m]  = *(const short8*)&A[aofb + m*512];
    if (kt+1 < NT) stage((cur^1)*8192, Ab, kt+1);
    __builtin_amdgcn_s_barrier();
    asm volatile("s_waitcnt lgkmcnt(0)" ::: "memory");
    __builtin_amdgcn_sched_barrier(0);
    __builtin_amdgcn_s_setprio(1);
#pragma unroll
    for (int m = 0; m < 4; ++m)
#pragma unroll
      for (int n = 0; n < 4; ++n)
        acc[m][n] = MFMA16(af[m], bfr[n], acc[m][n]);
    __builtin_amdgcn_s_setprio(0);
    __builtin_amdgcn_s_barrier();
    // ---- phase 1: A mf4-7; stage B(kt+2) -> cur (read-done after p0 BAR)
#pragma unroll
    for (int m = 0; m < 4; ++m) af[m] = *(const short8*)&A[aofb + (4+m)*512];
    if (kt+2 < NT) stage(16384 + cur*8192, Bb, kt+2);
    __builtin_amdgcn_s_barrier();
    asm volatile("s_waitcnt lgkmcnt(0)" ::: "memory");
    __builtin_amdgcn_sched_barrier(0);
    __builtin_amdgcn_s_setprio(1);
#pragma unroll
    for (int m = 0; m < 4; ++m)
#pragma unroll
      for (int n = 0; n < 4; ++n)
        acc[4+m][n] = MFMA16(af[m], bfr[n], acc[4+m][n]);
    __builtin_amdgcn_s_setprio(0);
    if (kt + 2 < NT) asm volatile("s_waitcnt vmcnt(2)" ::: "memory");
    else             asm volatile("s_waitcnt vmcnt(0)" ::: "memory");
    __builtin_amdgcn_s_barrier();
  }

  // epilogue: e = exp(s) (no max-sub: |s| <~ 6), bf16 store, rowsum atomics
  ushort* sb = scores + (size_t)b*2048*2048;
#pragma unroll
  for (int m = 0; m < 8; ++m){
    const int rm = m0 + wr*128 + m*16 + quad*4;
    float rs[4] = {0.f,0.f,0.f,0.f};
#pragma unroll
    for (int n = 0; n < 4; ++n){
      const int cn = n0 + wc*64 + n*16 + l15;
#pragma unroll
      for (int r = 0; r < 4; ++r){
        float e = __expf(acc[m][n][r]);
        ushort eb = f2bf(e);
        sb[(size_t)(rm + r)*2048 + cn] = eb;
        rs[r] += bf2f(eb);
      }
    }
#pragma unroll
    for (int r = 0; r < 4; ++r){
      float p2 = rs[r];
      p2 += __shfl_xor(p2, 1); p2 += __shfl_xor(p2, 2);
      p2 += __shfl_xor(p2, 4); p2 += __shfl_xor(p2, 8);
      if (l15 == 0)
        atomicAdd(&rowsum[(size_t)b*2048 + rm + r], p2);
    }
  }
}

// ---------------------------------------------------------------------------
// pv8: attn = (E @ X) / l. 256x128, BK=64, 8 waves, 96KB dbuf, counted vmcnt.
// (unchanged -- best measured performer, 0 conflicts)
// ---------------------------------------------------------------------------
__global__ __launch_bounds__(512)
void pv8(const ushort* __restrict__ P, const ushort* __restrict__ XT,
         const float* __restrict__ rowsum, ushort* __restrict__ attn)
{
  extern __shared__ __align__(16) ushort smem[];   // [2 bufs][A 16384 | B 8192]
  const int t = threadIdx.x, lane = t & 63, w = t >> 6;
  const int id = blockIdx.x;
  const int b = id & 7, s = id >> 3;
  const int m0 = (s >> 2) * 256;
  const int n0 = (s & 3) * 128;
  const ushort* Pb = P  + ((size_t)b*2048 + m0)*2048;
  const ushort* Xb = XT + ((size_t)b*512  + n0)*2048;
  const int wr = w >> 1, wc = w & 1;
  const int l15 = lane & 15, quad = lane >> 4;
  const int c0  = (quad ^ (l15 & 7)) * 8;
  const int srow = lane >> 3;
  const int skc  = ((lane & 7) ^ srow) * 8;

  floatx4 acc[4][4];
#pragma unroll
  for (int i = 0; i < 4; ++i)
#pragma unroll
    for (int j = 0; j < 4; ++j) acc[i][j] = (floatx4){0.f,0.f,0.f,0.f};

  auto stageA = [&](int buf, int kt, int h){
    ushort* base = smem + buf*24576 + h*8192;
#pragma unroll
    for (int r = 0; r < 2; ++r){
      const int rw = r*8 + w;
      gld16(base + rw*512,
            Pb + (size_t)(h*128 + rw*8 + srow)*2048 + kt*64 + skc);
    }
  };
  auto stageB = [&](int buf, int kt){
    ushort* base = smem + buf*24576 + 16384;
#pragma unroll
    for (int r = 0; r < 2; ++r){
      const int rw = r*8 + w;
      gld16(base + rw*512,
            Xb + (size_t)(rw*8 + srow)*2048 + kt*64 + skc);
    }
  };

  stageA(0, 0, 0);
  stageA(0, 0, 1);
  stageB(0, 0);
  stageB(1, 1);
  asm volatile("s_waitcnt vmcnt(2)" ::: "memory");
  __builtin_amdgcn_s_barrier();

  short8 af[2][2], bfr[4][2];
  const int NT = 32;

  for (int kt = 0; kt < NT; ++kt){
    const int cur = kt & 1;
    const ushort* A  = smem + cur*24576;
    const ushort* Bt = A + 16384;

#pragma unroll
    for (int ni = 0; ni < 4; ++ni)
#pragma unroll
      for (int ks = 0; ks < 2; ++ks)
        bfr[ni][ks] = *(const short8*)
          &Bt[(wc*64 + ni*16 + l15)*64 + (c0 ^ (ks*32))];
#pragma unroll
    for (int mi = 0; mi < 2; ++mi)
#pragma unroll
      for (int ks = 0; ks < 2; ++ks)
        af[mi][ks] = *(const short8*)
          &A[(wr*64 + mi*16 + l15)*64 + (c0 ^ (ks*32))];
    if (kt+1 < NT) stageA(cur^1, kt+1, 0);
    __builtin_amdgcn_s_barrier();
    asm volatile("s_waitcnt lgkmcnt(0)" ::: "memory");
    __builtin_amdgcn_sched_barrier(0);
    __builtin_amdgcn_s_setprio(1);
#pragma unroll
    for (int mi = 0; mi < 2; ++mi)
#pragma unroll
      for (int ni = 0; ni < 4; ++ni)
#pragma unroll
        for (int ks = 0; ks < 2; ++ks)
          acc[mi][ni] = MFMA16(af[mi][ks], bfr[ni][ks], acc[mi][ni]);
    __builtin_amdgcn_s_setprio(0);
    __builtin_amdgcn_s_barrier();

#pragma unroll
    for (int mi = 0; mi < 2; ++mi)
#pragma unroll
      for (int ks = 0; ks < 2; ++ks)
        af[mi][ks] = *(const short8*)
          &A[(wr*64 + (2+mi)*16 + l15)*64 + (c0 ^ (ks*32))];
    if (kt+1 < NT) stageA(cur^1, kt+1, 1);
    if (kt+2 < NT) stageB(cur, kt+2);
    __builtin_amdgcn_s_barrier();
    asm volatile("s_waitcnt lgkmcnt(0)" ::: "memory");
    __builtin_amdgcn_sched_barrier(0);
    __builtin_amdgcn_s_setprio(1);
#pragma unroll
    for (int mi = 0; mi < 2; ++mi)
#pragma unroll
      for (int ni = 0; ni < 4; ++ni)
#pragma unroll
        for (int ks = 0; ks < 2; ++ks)
          acc[2+mi][ni] = MFMA16(af[mi][ks], bfr[ni][ks], acc[2+mi][ni]);
    __builtin_amdgcn_s_setprio(0);
    if (kt + 2 < NT) asm volatile("s_waitcnt vmcnt(2)" ::: "memory");
    else             asm volatile("s_waitcnt vmcnt(0)" ::: "memory");
    __builtin_amdgcn_s_barrier();
  }

  ushort* ab = attn + (size_t)b*2048*512;
#pragma unroll
  for (int m = 0; m < 4; ++m){
    const int rm = m0 + wr*64 + m*16 + quad*4;
    float inv[4];
#pragma unroll
    for (int r = 0; r < 4; ++r)
      inv[r] = 1.0f / rowsum[(size_t)b*2048 + rm + r];
#pragma unroll
    for (int n = 0; n < 4; ++n){
      const int cn = n0 + wc*64 + n*16 + l15;
#pragma unroll
      for (int r = 0; r < 4; ++r)
        ab[(size_t)(rm + r)*512 + cn] = f2bf(acc[m][n][r] * inv[r]);
    }
  }
}

// ---------------------------------------------------------------------------
// res_rms1: h = rmsnorm(x + attn)*n1w -> bf16 in-place over attn buffer.
// ---------------------------------------------------------------------------
__global__ __launch_bounds__(256)
void res_rms1(const float* __restrict__ x, const float* __restrict__ n1w,
              ushort* __restrict__ ah)
{
  const int wid = threadIdx.x >> 6, lane = threadIdx.x & 63;
  const size_t row = (size_t)blockIdx.x*4 + wid;
  ushort* ar = ah + row*512;
  const float* xr = x + row*512;
  ushort4 a0 = *(const ushort4*)&ar[lane*8];
  ushort4 a1 = *(const ushort4*)&ar[lane*8 + 4];
  float4 x0 = ld4(xr + lane*8), x1 = ld4(xr + lane*8 + 4);
  float h[8];
  h[0]=x0.x+bf2f(a0.x); h[1]=x0.y+bf2f(a0.y); h[2]=x0.z+bf2f(a0.z); h[3]=x0.w+bf2f(a0.w);
  h[4]=x1.x+bf2f(a1.x); h[5]=x1.y+bf2f(a1.y); h[6]=x1.z+bf2f(a1.z); h[7]=x1.w+bf2f(a1.w);
  float ss = 0.f;
#pragma unroll
  for (int e=0;e<8;++e) ss += h[e]*h[e];
#pragma unroll
  for (int s=1;s<64;s<<=1) ss += __shfl_xor(ss, s);
  const float rr = rsqrtf(ss*(1.0f/512.0f) + EPS_F);
  ushort4 o0, o1;
  o0.x=f2bf(h[0]*rr*n1w[lane*8+0]); o0.y=f2bf(h[1]*rr*n1w[lane*8+1]);
  o0.z=f2bf(h[2]*rr*n1w[lane*8+2]); o0.w=f2bf(h[3]*rr*n1w[lane*8+3]);
  o1.x=f2bf(h[4]*rr*n1w[lane*8+4]); o1.y=f2bf(h[5]*rr*n1w[lane*8+5]);
  o1.z=f2bf(h[6]*rr*n1w[lane*8+6]); o1.w=f2bf(h[7]*rr*n1w[lane*8+7]);
  *(ushort4*)&ar[lane*8]     = o0;
  *(ushort4*)&ar[lane*8 + 4] = o1;
}

// ---------------------------------------------------------------------------
// ffn2: proj = hbf @ W1 + b1 (W1T), g = gelu(x1)*x2. 256x128 template,
// 2-bit swizzle key. grid 512. (acc 64 + ~60 fits the (512,4) 128-reg cap)
// ---------------------------------------------------------------------------
__global__ __launch_bounds__(512, 4)
void ffn2(const ushort* __restrict__ hbf, const ushort* __restrict__ W1T,
          const float* __restrict__ b1, ushort* __restrict__ gbuf)
{
  extern __shared__ __align__(16) ushort smem[];
  const int t = threadIdx.x, lane = t & 63, w = t >> 6;
  const int id = blockIdx.x;
  const int xcd = id & 7, sl = id >> 3;            // sl 0..63
  const int m0 = (xcd*8 + (sl >> 3)) * 256;
  const int n0 = (sl & 7) * 64;
  const ushort* Ab = hbf + (size_t)m0*512;
  const int wr = w >> 1, wc = w & 1;
  const int l15 = lane & 15, quad = lane >> 4;
  const int rl = lane >> 2;
  const int cl = (lane & 3) ^ ((lane >> 3) & 3);
  const int sw = ((l15 >> 1) & 3) * 8;
  int aoff[4], boff[4];
#pragma unroll
  for (int m = 0; m < 4; ++m)
    aoff[m] = ((wr*64 + m*16 + l15)*32 + quad*8) ^ sw;
#pragma unroll
  for (int n = 0; n < 4; ++n)
    boff[n] = ((wc*64 + n*16 + l15)*32 + quad*8) ^ sw;
  const size_t aS0 = (size_t)(w*16 + rl)*512 + cl*8;
  const size_t aS1 = aS0 + (size_t)128*512;
  const int br = w*16 + rl;                        // B tile row 0..127
  const int bgrow = ((br >> 5) & 1)*512 + n0 + (br >> 6)*32 + (br & 31);
  const size_t bS0 = (size_t)bgrow*512 + cl*8;
  const int aD = w*512, bD = 16384 + w*512;

  floatx4 acc[4][4];
#pragma unroll
  for (int i = 0; i < 4; ++i)
#pragma unroll
    for (int j = 0; j < 4; ++j) acc[i][j] = (floatx4){0.f,0.f,0.f,0.f};

  const int NT = 16;
  gld16(smem + aD,        Ab + aS0);
  gld16(smem + 4096 + aD, Ab + aS1);
  gld16(smem + bD,        W1T + bS0);
  gld16(smem + 4096 + bD, W1T + bS0 + 32);
  asm volatile("s_waitcnt vmcnt(1)" ::: "memory");
  __builtin_amdgcn_s_barrier();

  short8 af[2], bfr[4];
  for (int kt = 0; kt < NT; ++kt){
    const int cur = kt & 1;
    const ushort* A  = smem + cur*8192;
    const ushort* Bt = smem + 16384 + cur*4096;
#pragma unroll
    for (int n = 0; n < 4; ++n) bfr[n] = *(const short8*)&Bt[boff[n]];
#pragma unroll
    for (int m = 0; m < 2; ++m) af[m] = *(const short8*)&A[aoff[m]];
    if (kt+1 < NT){
      ushort* d = smem + (cur^1)*8192;
      const size_t ko = (size_t)(kt+1)*32;
      gld16(d + aD,        Ab + aS0 + ko);
      gld16(d + 4096 + aD, Ab + aS1 + ko);
    }
    __builtin_amdgcn_s_barrier();
    asm volatile("s_waitcnt lgkmcnt(0)" ::: "memory");
    __builtin_amdgcn_sched_barrier(0);
    __builtin_amdgcn_s_setprio(1);
#pragma unroll
    for (int m = 0; m < 2; ++m)
#pragma unroll
      for (int n = 0; n < 4; ++n)
        acc[m][n] = MFMA16(af[m], bfr[n], acc[m][n]);
    __builtin_amdgcn_s_setprio(0);
    __builtin_amdgcn_s_barrier();
#pragma unroll
    for (int m = 0; m < 2; ++m) af[m] = *(const short8*)&A[aoff[2+m]];
    if (kt+2 < NT)
      gld16(smem + cur*4096 + bD, W1T + bS0 + (size_t)(kt+2)*32);
    __builtin_amdgcn_s_barrier();
    asm volatile("s_waitcnt lgkmcnt(0)" ::: "memory");
    __builtin_amdgcn_sched_barrier(0);
    __builtin_amdgcn_s_setprio(1);
#pragma unroll
    for (int m = 0; m < 2; ++m)
#pragma unroll
      for (int n = 0; n < 4; ++n)
        acc[2+m][n] = MFMA16(af[m], bfr[n], acc[2+m][n]);
    __builtin_amdgcn_s_setprio(0);
    if (kt + 2 < NT) asm volatile("s_waitcnt vmcnt(1)" ::: "memory");
    else             asm volatile("s_waitcnt vmcnt(0)" ::: "memory");
    __builtin_amdgcn_s_barrier();
  }

#pragma unroll
  for (int m = 0; m < 4; ++m){
#pragma unroll
    for (int n = 0; n < 2; ++n){
      const int col = n0 + wc*32 + n*16 + l15;
      const float bb1 = b1[col], bb2 = b1[512 + col];
#pragma unroll
      for (int r = 0; r < 4; ++r){
        const int row = m0 + wr*64 + m*16 + quad*4 + r;
        float x1 = acc[m][n][r]     + bb1;
        float x2 = acc[m][n+2][r]   + bb2;
        float gl = 0.5f*x1*(1.0f + erff(x1*0.70710678118654752f));
        gbuf[(size_t)row*512 + col] = f2bf(gl*x2);
      }
    }
  }
}

// ---------------------------------------------------------------------------
// ff2: ff = g @ W2 (via W2T). 256x128 template, 2-bit swizzle. grid 256.
// ---------------------------------------------------------------------------
__global__ __launch_bounds__(512, 4)
void ff2(const ushort* __restrict__ gb, const ushort* __restrict__ W2T,
         ushort* __restrict__ ff)
{
  extern __shared__ __align__(16) ushort smem[];
  const int t = threadIdx.x, lane = t & 63, w = t >> 6;
  const int id = blockIdx.x;
  const int xcd = id & 7, sl = id >> 3;            // sl 0..31
  const int m0 = (xcd*8 + (sl >> 2)) * 256;
  const int n0 = (sl & 3) * 128;
  const ushort* Ab = gb  + (size_t)m0*512;
  const ushort* Bb = W2T + (size_t)n0*512;
  const int wr = w >> 1, wc = w & 1;
  const int l15 = lane & 15, quad = lane >> 4;
  const int rl = lane >> 2;
  const int cl = (lane & 3) ^ ((lane >> 3) & 3);
  const int sw = ((l15 >> 1) & 3) * 8;
  int aoff[4], boff[4];
#pragma unroll
  for (int m = 0; m < 4; ++m)
    aoff[m] = ((wr*64 + m*16 + l15)*32 + quad*8) ^ sw;
#pragma unroll
  for (int n = 0; n < 4; ++n)
    boff[n] = ((wc*64 + n*16 + l15)*32 + quad*8) ^ sw;
  const size_t aS0 = (size_t)(w*16 + rl)*512 + cl*8;
  const size_t aS1 = aS0 + (size_t)128*512;
  const size_t bS0 = (size_t)(w*16 + rl)*512 + cl*8;
  const int aD = w*512, bD = 16384 + w*512;

  floatx4 acc[4][4];
#pragma unroll
  for (int i = 0; i < 4; ++i)
#pragma unroll
    for (int j = 0; j < 4; ++j) acc[i][j] = (floatx4){0.f,0.f,0.f,0.f};

  const int NT = 16;
  gld16(smem + aD,        Ab + aS0);
  gld16(smem + 4096 + aD, Ab + aS1);
  gld16(smem + bD,        Bb + bS0);
  gld16(smem + 4096 + bD, Bb + bS0 + 32);
  asm volatile("s_waitcnt vmcnt(1)" ::: "memory");
  __builtin_amdgcn_s_barrier();

  short8 af[2], bfr[4];
  for (int kt = 0; kt < NT; ++kt){
    const int cur = kt & 1;
    const ushort* A  = smem + cur*8192;
    const ushort* Bt = smem + 16384 + cur*4096;
#pragma unroll
    for (int n = 0; n < 4; ++n) bfr[n] = *(const short8*)&Bt[boff[n]];
#pragma unroll
    for (int m = 0; m < 2; ++m) af[m] = *(const short8*)&A[aoff[m]];
    if (kt+1 < NT){
      ushort* d = smem + (cur^1)*8192;
      const size_t ko = (size_t)(kt+1)*32;
      gld16(d + aD,        Ab + aS0 + ko);
      gld16(d + 4096 + aD, Ab + aS1 + ko);
    }
    __builtin_amdgcn_s_barrier();
    asm volatile("s_waitcnt lgkmcnt(0)" ::: "memory");
    __builtin_amdgcn_sched_barrier(0);
    __builtin_amdgcn_s_setprio(1);
#pragma unroll
    for (int m = 0; m < 2; ++m)
#pragma unroll
      for (int n = 0; n < 4; ++n)
        acc[m][n] = MFMA16(af[m], bfr[n], acc[m][n]);
    __builtin_amdgcn_s_setprio(0);
    __builtin_amdgcn_s_barrier();
#pragma unroll
    for (int m = 0; m < 2; ++m) af[m] = *(const short8*)&A[aoff[2+m]];
    if (kt+2 < NT)
      gld16(smem + cur*4096 + bD, Bb + bS0 + (size_t)(kt+2)*32);
    __builtin_amdgcn_s_barrier();
    asm volatile("s_waitcnt lgkmcnt(0)" ::: "memory");
    __builtin_amdgcn_sched_barrier(0);
    __builtin_amdgcn_s_setprio(1);
#pragma unroll
    for (int m = 0; m < 2; ++m)
#pragma unroll
      for (int n = 0; n < 4; ++n)
        acc[2+m][n] = MFMA16(af[m], bfr[n], acc[2+m][n]);
    __builtin_amdgcn_s_setprio(0);
    if (kt + 2 < NT) asm volatile("s_waitcnt vmcnt(1)" ::: "memory");
    else             asm volatile("s_waitcnt vmcnt(0)" ::: "memory");
    __builtin_amdgcn_s_barrier();
  }

#pragma unroll
  for (int m = 0; m < 4; ++m){
    const int rm = m0 + wr*64 + m*16 + quad*4;
#pragma unroll
    for (int n = 0; n < 4; ++n){
      const int cn = n0 + wc*64 + n*16 + l15;
#pragma unroll
      for (int r = 0; r < 4; ++r)
        ff[(size_t)(rm + r)*512 + cn] = f2bf(acc[m][n][r]);
    }
  }
}

// ---------------------------------------------------------------------------
// res_rms2: y = h + ff + b2; out = rmsnorm(y)*n2w (fp32). One wave per row.
// ---------------------------------------------------------------------------
__global__ __launch_bounds__(256)
void res_rms2(const ushort* __restrict__ hbf, const ushort* __restrict__ ff,
              const float* __restrict__ b2, const float* __restrict__ n2w,
              float* __restrict__ out)
{
  const int wid = threadIdx.x >> 6, lane = threadIdx.x & 63;
  const size_t row = (size_t)blockIdx.x*4 + wid;
  const ushort* hr = hbf + row*512;
  const ushort* fr = ff  + row*512;
  ushort4 h0 = *(const ushort4*)&hr[lane*8];
  ushort4 h1 = *(const ushort4*)&hr[lane*8 + 4];
  ushort4 f0 = *(const ushort4*)&fr[lane*8];
  ushort4 f1 = *(const ushort4*)&fr[lane*8 + 4];
  float4 bb0 = ld4(b2 + lane*8), bb1 = ld4(b2 + lane*8 + 4);
  float y[8];
  y[0]=bf2f(h0.x)+bf2f(f0.x)+bb0.x; y[1]=bf2f(h0.y)+bf2f(f0.y)+bb0.y;
  y[2]=bf2f(h0.z)+bf2f(f0.z)+bb0.z; y[3]=bf2f(h0.w)+bf2f(f0.w)+bb0.w;
  y[4]=bf2f(h1.x)+bf2f(f1.x)+bb1.x; y[5]=bf2f(h1.y)+bf2f(f1.y)+bb1.y;
  y[6]=bf2f(h1.z)+bf2f(f1.z)+bb1.z; y[7]=bf2f(h1.w)+bf2f(f1.w)+bb1.w;
  float ss = 0.f;
#pragma unroll
  for (int e=0;e<8;++e) ss += y[e]*y[e];
#pragma unroll
  for (int s=1;s<64;s<<=1) ss += __shfl_xor(ss, s);
  const float rr = rsqrtf(ss*(1.0f/512.0f) + EPS_F);
  float4 w0 = ld4(n2w + lane*8), w1 = ld4(n2w + lane*8 + 4);
  float* orow = out + row*512;
  float4 o0, o1;
  o0.x=y[0]*rr*w0.x; o0.y=y[1]*rr*w0.y; o0.z=y[2]*rr*w0.z; o0.w=y[3]*rr*w0.w;
  o1.x=y[4]*rr*w1.x; o1.y=y[5]*rr*w1.y; o1.z=y[6]*rr*w1.z; o1.w=y[7]*rr*w1.w;
  *(float4*)(orow + lane*8)     = o0;
  *(float4*)(orow + lane*8 + 4) = o1;
}

// ---------------------------------------------------------------------------
extern "C" void kernel_launch(void* const* d_in, const int* in_sizes, int n_in,
                              void* d_out, int out_size, void* d_ws, size_t ws_size,
                              hipStream_t stream)
{
  const float* x   = (const float*)d_in[0];
  const float* q   = (const float*)d_in[1];
  const float* k   = (const float*)d_in[2];
  const float* W1  = (const float*)d_in[3];
  const float* b1  = (const float*)d_in[4];
  const float* W2  = (const float*)d_in[5];
  const float* b2  = (const float*)d_in[6];
  const float* n1w = (const float*)d_in[7];
  const float* n2w = (const float*)d_in[8];
  float* out = (float*)d_out;

  // ws (ushort units): scores 64MB | XT 16MB | Qbf 16MB | Kbf 16MB
  //                    | W1T 1MB | W2T .5MB | rowsum 64KB(float)
  ushort* scoresP = (ushort*)d_ws;
  ushort* XT  = scoresP + (size_t)8*2048*2048;
  ushort* Qbf = XT  + (size_t)8*512*2048;
  ushort* Kbf = Qbf + (size_t)8*2048*512;
  ushort* W1T = Kbf + (size_t)8*2048*512;
  ushort* W2T = W1T + (size_t)1024*512;
  float*  rowsum = (float*)(W2T + (size_t)512*512);
  ushort* attn = Qbf;      // alias: Qbf dead after qk3
  ushort* hbf  = Qbf;      // res_rms1 rewrites attn in place
  ushort* gbuf = Kbf;      // alias: Kbf dead after qk3
  ushort* ffb  = scoresP;  // alias: scores dead after pv8

  hipMemsetAsync(rowsum, 0, (size_t)8*2048*sizeof(float), stream);
  prep     <<<dim3(10432),  256, 0, stream>>>(q, k, x, W1, W2, Qbf, Kbf, XT, W1T, W2T);
  qk3      <<<dim3(512),    512, 65536, stream>>>(Qbf, Kbf, scoresP, rowsum);
  pv8      <<<dim3(256),    512, 98304, stream>>>(scoresP, XT, rowsum, attn);
  res_rms1 <<<dim3(4096),   256, 0, stream>>>(x, n1w, hbf);
  ffn2     <<<dim3(512),    512, 49152, stream>>>(hbf, W1T, b1, gbuf);
  ff2      <<<dim3(256),    512, 49152, stream>>>(gbuf, W2T, ffb);
  res_rms2 <<<dim3(4096),   256, 0, stream>>>(hbf, ffb, b2, n2w, out);
}

// Round 6
// 294.252 us; speedup vs baseline: 1.9621x; 1.0291x over previous
//
#include <hip/hip_runtime.h>
#include <math.h>

static constexpr float EPS_F = 1.1920929e-07f;           // finfo(float32).eps
static constexpr float SCL   = 0.044194173824159216f;    // 1/sqrt(512)

typedef __attribute__((ext_vector_type(8))) short  short8;   // 8 bf16 (4 VGPRs)
typedef __attribute__((ext_vector_type(4))) float  floatx4;  // MFMA C/D

__device__ __forceinline__ float4 ld4(const float* p){ return *(const float4*)p; }
__device__ __forceinline__ ushort f2bf(float f){
  union { float f; unsigned u; } v; v.f = f;
  return (ushort)((v.u + 0x7FFFu + ((v.u >> 16) & 1u)) >> 16);   // RNE
}
__device__ __forceinline__ float bf2f(ushort h){
  union { unsigned u; float f; } v; v.u = ((unsigned)h) << 16;
  return v.f;
}
#define MFMA16(A,B,C) __builtin_amdgcn_mfma_f32_16x16x32_bf16((A),(B),(C),0,0,0)

// async global->LDS, 16B/lane. LDS dst = wave-uniform base + lane*16.
__device__ __forceinline__ void gld16(void* lds, const void* g){
  __builtin_amdgcn_global_load_lds(
      (const __attribute__((address_space(1))) unsigned int*)g,
      (__attribute__((address_space(3))) unsigned int*)lds, 16, 0, 0);
}

// ===========================================================================
// Swizzle (verified on HW, conflicts==0): rows are 64B (32 bf16). 2-bit key:
// element (row R, 8-elem chunk c) at LDS elem off R*32 + 8*(c ^ ((R>>1)&3)).
// Staging (linear gld dst): lane L -> row base+(L>>2), chunk (L&3)^((L>>3)&3).
// REGISTER RULE (R4 lesson): acc[8][4] (128 f32) needs the full 256-reg
// budget -> never combine with __launch_bounds__(512,4) (spills to scratch).
// acc[4][4] (64 f32) + ~60 operand regs fits the (512,4) 128-reg cap ->
// 4 waves/SIMD -> 2 blocks/CU -> cross-block overlap of epilogue/staging
// (R5 lesson: 1-block/CU lockstep leaves the MFMA pipe idle 75%).
// ===========================================================================

// ---------------------------------------------------------------------------
// prep: merged cvt(q,k) + transpose(x) + transpose(W1) + transpose(W2).
// ---------------------------------------------------------------------------
__global__ __launch_bounds__(256)
void prep(const float* __restrict__ q, const float* __restrict__ k,
          const float* __restrict__ x, const float* __restrict__ W1,
          const float* __restrict__ W2,
          ushort* __restrict__ Qb, ushort* __restrict__ Kb,
          ushort* __restrict__ XT, ushort* __restrict__ W1T,
          ushort* __restrict__ W2T)
{
  const int bi = blockIdx.x, t = threadIdx.x;
  if (bi < 8192){
    const size_t i4 = ((size_t)bi*256 + t)*4;
    float4 v = ld4(q + i4);
    ushort4 o;
    o.x=f2bf(v.x*SCL); o.y=f2bf(v.y*SCL); o.z=f2bf(v.z*SCL); o.w=f2bf(v.w*SCL);
    *(ushort4*)(Qb + i4) = o;
    float4 u = ld4(k + i4);
    o.x=f2bf(u.x); o.y=f2bf(u.y); o.z=f2bf(u.z); o.w=f2bf(u.w);
    *(ushort4*)(Kb + i4) = o;
    return;
  }
  const float* in; ushort* out; int R, C, c0, r0; size_t boff;
  if (bi < 10240){
    const int id = bi - 8192;
    in = x; out = XT; R = 2048; C = 512;
    boff = (size_t)(id >> 8) * R * C;
    c0 = (id & 7)*64; r0 = ((id >> 3) & 31)*64;
  } else if (bi < 10368){
    const int id = bi - 10240;
    in = W1; out = W1T; R = 512; C = 1024; boff = 0;
    c0 = (id & 15)*64; r0 = (id >> 4)*64;
  } else {
    const int id = bi - 10368;
    in = W2; out = W2T; R = 512; C = 512; boff = 0;
    c0 = (id & 7)*64; r0 = (id >> 3)*64;
  }
  __shared__ __align__(16) ushort tile[64*68];
#pragma unroll
  for (int it = 0; it < 4; ++it){
    int f = t + it*256, r = f >> 4, c4 = f & 15;
    float4 v = ld4(in + boff + (size_t)(r0+r)*C + c0 + c4*4);
    ushort4 o; o.x=f2bf(v.x); o.y=f2bf(v.y); o.z=f2bf(v.z); o.w=f2bf(v.w);
    *(ushort4*)&tile[r*68 + c4*4] = o;
  }
  __syncthreads();
#pragma unroll
  for (int it = 0; it < 4; ++it){
    int f = t + it*256, c = f >> 4, q4 = f & 15;
    ushort4 o;
    o.x = tile[(q4*4+0)*68 + c];
    o.y = tile[(q4*4+1)*68 + c];
    o.z = tile[(q4*4+2)*68 + c];
    o.w = tile[(q4*4+3)*68 + c];
    *(ushort4*)(out + boff + (size_t)(c0+c)*R + r0 + q4*4) = o;
  }
}

// ---------------------------------------------------------------------------
// qk4: E = exp(Q*SCL @ K^T) (bf16) + per-row sums (atomic).
// 256x128 tile, BK=32, 8 waves (4M x 2N, wave 64x64), 48KB LDS dbuf,
// acc 64 f32 -> fits (512,4) 128-reg cap -> 2 blocks/CU: co-resident block's
// K-loop hides this block's epilogue/staging stalls. 2-bit swizzle (0 confl).
// grid 1024: b=id&7 (batch per XCD); m fastest (B-panel reuse in L2).
// Schedule/K-tile: p0 {ds B all + A m0,m1; stage A(kt+1) [2]; BAR; lgkm;
// 8 MFMA; BAR} p1 {ds A m2,m3; stage B(kt+2) [1]; BAR; lgkm; 8 MFMA;
// vmcnt(1) (keep B(kt+2) in flight; 0 at tail); BAR}.
// ---------------------------------------------------------------------------
__global__ __launch_bounds__(512, 4)
void qk4(const ushort* __restrict__ Qbf, const ushort* __restrict__ Kbf,
         ushort* __restrict__ scores, float* __restrict__ rowsum)
{
  extern __shared__ __align__(16) ushort smem[];  // A 2x8192 | B 2x4096 elems
  const int t = threadIdx.x, lane = t & 63, w = t >> 6;
  const int id = blockIdx.x;
  const int b = id & 7, s = id >> 3;               // s 0..127
  const int m0 = (s & 7) * 256, n0 = (s >> 3) * 128;
  const ushort* Ab = Qbf + ((size_t)b*2048 + m0)*512;
  const ushort* Bb = Kbf + ((size_t)b*2048 + n0)*512;
  const int wr = w >> 1, wc = w & 1;               // wave tile 64m x 64n
  const int l15 = lane & 15, quad = lane >> 4;
  const int sw = ((l15 >> 1) & 3) * 8;             // 2-bit chunk key
  const int rl = lane >> 2;                        // staging row-in-16
  const int cl = (lane & 3) ^ ((lane >> 3) & 3);   // staging chunk
  int aoff[4], boff[4];
#pragma unroll
  for (int m = 0; m < 4; ++m)
    aoff[m] = (wr*64 + m*16 + l15)*32 + (quad*8 ^ sw);
#pragma unroll
  for (int n = 0; n < 4; ++n)
    boff[n] = (wc*64 + n*16 + l15)*32 + (quad*8 ^ sw);
  // staging sources (element offsets; + kt*32 per tile)
  const size_t aS0 = (size_t)(w*16 + rl)*512 + cl*8;          // rows w*16+rl
  const size_t aS1 = aS0 + (size_t)128*512;                   // rows +128
  const size_t bS0 = (size_t)(w*16 + rl)*512 + cl*8;
  const int aD = w*512, bD = 16384 + w*512;                   // lds elem bases

  floatx4 acc[4][4];
#pragma unroll
  for (int i = 0; i < 4; ++i)
#pragma unroll
    for (int j = 0; j < 4; ++j) acc[i][j] = (floatx4){0.f,0.f,0.f,0.f};

  const int NT = 16;
  // prologue: A0 (2 ops), B0 (1), B1 (1) -> wait to 1 outstanding
  gld16(smem + aD,        Ab + aS0);
  gld16(smem + 4096 + aD, Ab + aS1);
  gld16(smem + bD,        Bb + bS0);
  gld16(smem + 4096 + bD, Bb + bS0 + 32);
  asm volatile("s_waitcnt vmcnt(1)" ::: "memory");
  __builtin_amdgcn_s_barrier();

  short8 af[2], bfr[4];
  for (int kt = 0; kt < NT; ++kt){
    const int cur = kt & 1;
    const ushort* A  = smem + cur*8192;
    const ushort* Bt = smem + 16384 + cur*4096;
    // ---- phase 0
#pragma unroll
    for (int n = 0; n < 4; ++n) bfr[n] = *(const short8*)&Bt[boff[n]];
#pragma unroll
    for (int m = 0; m < 2; ++m) af[m] = *(const short8*)&A[aoff[m]];
    if (kt+1 < NT){
      ushort* d = smem + (cur^1)*8192;
      const size_t ko = (size_t)(kt+1)*32;
      gld16(d + aD,        Ab + aS0 + ko);
      gld16(d + 4096 + aD, Ab + aS1 + ko);
    }
    __builtin_amdgcn_s_barrier();
    asm volatile("s_waitcnt lgkmcnt(0)" ::: "memory");
    __builtin_amdgcn_sched_barrier(0);
    __builtin_amdgcn_s_setprio(1);
#pragma unroll
    for (int m = 0; m < 2; ++m)
#pragma unroll
      for (int n = 0; n < 4; ++n)
        acc[m][n] = MFMA16(af[m], bfr[n], acc[m][n]);
    __builtin_amdgcn_s_setprio(0);
    __builtin_amdgcn_s_barrier();
    // ---- phase 1
#pragma unroll
    for (int m = 0; m < 2; ++m) af[m] = *(const short8*)&A[aoff[2+m]];
    if (kt+2 < NT)
      gld16(smem + 16384 + cur*4096 + (bD - 16384),
            Bb + bS0 + (size_t)(kt+2)*32);
    __builtin_amdgcn_s_barrier();
    asm volatile("s_waitcnt lgkmcnt(0)" ::: "memory");
    __builtin_amdgcn_sched_barrier(0);
    __builtin_amdgcn_s_setprio(1);
#pragma unroll
    for (int m = 0; m < 2; ++m)
#pragma unroll
      for (int n = 0; n < 4; ++n)
        acc[2+m][n] = MFMA16(af[m], bfr[n], acc[2+m][n]);
    __builtin_amdgcn_s_setprio(0);
    if (kt + 2 < NT) asm volatile("s_waitcnt vmcnt(1)" ::: "memory");
    else             asm volatile("s_waitcnt vmcnt(0)" ::: "memory");
    __builtin_amdgcn_s_barrier();
  }

  // epilogue: e = exp(s) (no max-sub: |s| <~ 6), bf16 store, rowsum atomics
  ushort* sb = scores + (size_t)b*2048*2048;
#pragma unroll
  for (int m = 0; m < 4; ++m){
    const int rm = m0 + wr*64 + m*16 + quad*4;
    float rs[4] = {0.f,0.f,0.f,0.f};
#pragma unroll
    for (int n = 0; n < 4; ++n){
      const int cn = n0 + wc*64 + n*16 + l15;
#pragma unroll
      for (int r = 0; r < 4; ++r){
        float e = __expf(acc[m][n][r]);
        ushort eb = f2bf(e);
        sb[(size_t)(rm + r)*2048 + cn] = eb;
        rs[r] += bf2f(eb);
      }
    }
#pragma unroll
    for (int r = 0; r < 4; ++r){
      float p2 = rs[r];
      p2 += __shfl_xor(p2, 1); p2 += __shfl_xor(p2, 2);
      p2 += __shfl_xor(p2, 4); p2 += __shfl_xor(p2, 8);
      if (l15 == 0)
        atomicAdd(&rowsum[(size_t)b*2048 + rm + r], p2);
    }
  }
}

// ---------------------------------------------------------------------------
// pv8: attn = (E @ X) / l. 256x128, BK=64, 8 waves, 96KB dbuf, counted vmcnt.
// (unchanged -- best measured performer, 0 conflicts)
// ---------------------------------------------------------------------------
__global__ __launch_bounds__(512)
void pv8(const ushort* __restrict__ P, const ushort* __restrict__ XT,
         const float* __restrict__ rowsum, ushort* __restrict__ attn)
{
  extern __shared__ __align__(16) ushort smem[];   // [2 bufs][A 16384 | B 8192]
  const int t = threadIdx.x, lane = t & 63, w = t >> 6;
  const int id = blockIdx.x;
  const int b = id & 7, s = id >> 3;
  const int m0 = (s >> 2) * 256;
  const int n0 = (s & 3) * 128;
  const ushort* Pb = P  + ((size_t)b*2048 + m0)*2048;
  const ushort* Xb = XT + ((size_t)b*512  + n0)*2048;
  const int wr = w >> 1, wc = w & 1;
  const int l15 = lane & 15, quad = lane >> 4;
  const int c0  = (quad ^ (l15 & 7)) * 8;
  const int srow = lane >> 3;
  const int skc  = ((lane & 7) ^ srow) * 8;

  floatx4 acc[4][4];
#pragma unroll
  for (int i = 0; i < 4; ++i)
#pragma unroll
    for (int j = 0; j < 4; ++j) acc[i][j] = (floatx4){0.f,0.f,0.f,0.f};

  auto stageA = [&](int buf, int kt, int h){
    ushort* base = smem + buf*24576 + h*8192;
#pragma unroll
    for (int r = 0; r < 2; ++r){
      const int rw = r*8 + w;
      gld16(base + rw*512,
            Pb + (size_t)(h*128 + rw*8 + srow)*2048 + kt*64 + skc);
    }
  };
  auto stageB = [&](int buf, int kt){
    ushort* base = smem + buf*24576 + 16384;
#pragma unroll
    for (int r = 0; r < 2; ++r){
      const int rw = r*8 + w;
      gld16(base + rw*512,
            Xb + (size_t)(rw*8 + srow)*2048 + kt*64 + skc);
    }
  };

  stageA(0, 0, 0);
  stageA(0, 0, 1);
  stageB(0, 0);
  stageB(1, 1);
  asm volatile("s_waitcnt vmcnt(2)" ::: "memory");
  __builtin_amdgcn_s_barrier();

  short8 af[2][2], bfr[4][2];
  const int NT = 32;

  for (int kt = 0; kt < NT; ++kt){
    const int cur = kt & 1;
    const ushort* A  = smem + cur*24576;
    const ushort* Bt = A + 16384;

#pragma unroll
    for (int ni = 0; ni < 4; ++ni)
#pragma unroll
      for (int ks = 0; ks < 2; ++ks)
        bfr[ni][ks] = *(const short8*)
          &Bt[(wc*64 + ni*16 + l15)*64 + (c0 ^ (ks*32))];
#pragma unroll
    for (int mi = 0; mi < 2; ++mi)
#pragma unroll
      for (int ks = 0; ks < 2; ++ks)
        af[mi][ks] = *(const short8*)
          &A[(wr*64 + mi*16 + l15)*64 + (c0 ^ (ks*32))];
    if (kt+1 < NT) stageA(cur^1, kt+1, 0);
    __builtin_amdgcn_s_barrier();
    asm volatile("s_waitcnt lgkmcnt(0)" ::: "memory");
    __builtin_amdgcn_sched_barrier(0);
    __builtin_amdgcn_s_setprio(1);
#pragma unroll
    for (int mi = 0; mi < 2; ++mi)
#pragma unroll
      for (int ni = 0; ni < 4; ++ni)
#pragma unroll
        for (int ks = 0; ks < 2; ++ks)
          acc[mi][ni] = MFMA16(af[mi][ks], bfr[ni][ks], acc[mi][ni]);
    __builtin_amdgcn_s_setprio(0);
    __builtin_amdgcn_s_barrier();

#pragma unroll
    for (int mi = 0; mi < 2; ++mi)
#pragma unroll
      for (int ks = 0; ks < 2; ++ks)
        af[mi][ks] = *(const short8*)
          &A[(wr*64 + (2+mi)*16 + l15)*64 + (c0 ^ (ks*32))];
    if (kt+1 < NT) stageA(cur^1, kt+1, 1);
    if (kt+2 < NT) stageB(cur, kt+2);
    __builtin_amdgcn_s_barrier();
    asm volatile("s_waitcnt lgkmcnt(0)" ::: "memory");
    __builtin_amdgcn_sched_barrier(0);
    __builtin_amdgcn_s_setprio(1);
#pragma unroll
    for (int mi = 0; mi < 2; ++mi)
#pragma unroll
      for (int ni = 0; ni < 4; ++ni)
#pragma unroll
        for (int ks = 0; ks < 2; ++ks)
          acc[2+mi][ni] = MFMA16(af[mi][ks], bfr[ni][ks], acc[2+mi][ni]);
    __builtin_amdgcn_s_setprio(0);
    if (kt + 2 < NT) asm volatile("s_waitcnt vmcnt(2)" ::: "memory");
    else             asm volatile("s_waitcnt vmcnt(0)" ::: "memory");
    __builtin_amdgcn_s_barrier();
  }

  ushort* ab = attn + (size_t)b*2048*512;
#pragma unroll
  for (int m = 0; m < 4; ++m){
    const int rm = m0 + wr*64 + m*16 + quad*4;
    float inv[4];
#pragma unroll
    for (int r = 0; r < 4; ++r)
      inv[r] = 1.0f / rowsum[(size_t)b*2048 + rm + r];
#pragma unroll
    for (int n = 0; n < 4; ++n){
      const int cn = n0 + wc*64 + n*16 + l15;
#pragma unroll
      for (int r = 0; r < 4; ++r)
        ab[(size_t)(rm + r)*512 + cn] = f2bf(acc[m][n][r] * inv[r]);
    }
  }
}

// ---------------------------------------------------------------------------
// res_rms1: h = rmsnorm(x + attn)*n1w -> bf16 in-place over attn buffer.
// ---------------------------------------------------------------------------
__global__ __launch_bounds__(256)
void res_rms1(const float* __restrict__ x, const float* __restrict__ n1w,
              ushort* __restrict__ ah)
{
  const int wid = threadIdx.x >> 6, lane = threadIdx.x & 63;
  const size_t row = (size_t)blockIdx.x*4 + wid;
  ushort* ar = ah + row*512;
  const float* xr = x + row*512;
  ushort4 a0 = *(const ushort4*)&ar[lane*8];
  ushort4 a1 = *(const ushort4*)&ar[lane*8 + 4];
  float4 x0 = ld4(xr + lane*8), x1 = ld4(xr + lane*8 + 4);
  float h[8];
  h[0]=x0.x+bf2f(a0.x); h[1]=x0.y+bf2f(a0.y); h[2]=x0.z+bf2f(a0.z); h[3]=x0.w+bf2f(a0.w);
  h[4]=x1.x+bf2f(a1.x); h[5]=x1.y+bf2f(a1.y); h[6]=x1.z+bf2f(a1.z); h[7]=x1.w+bf2f(a1.w);
  float ss = 0.f;
#pragma unroll
  for (int e=0;e<8;++e) ss += h[e]*h[e];
#pragma unroll
  for (int s=1;s<64;s<<=1) ss += __shfl_xor(ss, s);
  const float rr = rsqrtf(ss*(1.0f/512.0f) + EPS_F);
  ushort4 o0, o1;
  o0.x=f2bf(h[0]*rr*n1w[lane*8+0]); o0.y=f2bf(h[1]*rr*n1w[lane*8+1]);
  o0.z=f2bf(h[2]*rr*n1w[lane*8+2]); o0.w=f2bf(h[3]*rr*n1w[lane*8+3]);
  o1.x=f2bf(h[4]*rr*n1w[lane*8+4]); o1.y=f2bf(h[5]*rr*n1w[lane*8+5]);
  o1.z=f2bf(h[6]*rr*n1w[lane*8+6]); o1.w=f2bf(h[7]*rr*n1w[lane*8+7]);
  *(ushort4*)&ar[lane*8]     = o0;
  *(ushort4*)&ar[lane*8 + 4] = o1;
}

// ---------------------------------------------------------------------------
// ffn2: proj = hbf @ W1 + b1 (W1T), g = gelu(x1)*x2. 256x128 template,
// 2-bit swizzle key. grid 512.
// ---------------------------------------------------------------------------
__global__ __launch_bounds__(512, 4)
void ffn2(const ushort* __restrict__ hbf, const ushort* __restrict__ W1T,
          const float* __restrict__ b1, ushort* __restrict__ gbuf)
{
  extern __shared__ __align__(16) ushort smem[];
  const int t = threadIdx.x, lane = t & 63, w = t >> 6;
  const int id = blockIdx.x;
  const int xcd = id & 7, sl = id >> 3;            // sl 0..63
  const int m0 = (xcd*8 + (sl >> 3)) * 256;
  const int n0 = (sl & 7) * 64;
  const ushort* Ab = hbf + (size_t)m0*512;
  const int wr = w >> 1, wc = w & 1;
  const int l15 = lane & 15, quad = lane >> 4;
  const int rl = lane >> 2;
  const int cl = (lane & 3) ^ ((lane >> 3) & 3);
  const int sw = ((l15 >> 1) & 3) * 8;
  int aoff[4], boff[4];
#pragma unroll
  for (int m = 0; m < 4; ++m)
    aoff[m] = ((wr*64 + m*16 + l15)*32 + quad*8) ^ sw;
#pragma unroll
  for (int n = 0; n < 4; ++n)
    boff[n] = ((wc*64 + n*16 + l15)*32 + quad*8) ^ sw;
  const size_t aS0 = (size_t)(w*16 + rl)*512 + cl*8;
  const size_t aS1 = aS0 + (size_t)128*512;
  const int br = w*16 + rl;                        // B tile row 0..127
  const int bgrow = ((br >> 5) & 1)*512 + n0 + (br >> 6)*32 + (br & 31);
  const size_t bS0 = (size_t)bgrow*512 + cl*8;
  const int aD = w*512, bD = 16384 + w*512;

  floatx4 acc[4][4];
#pragma unroll
  for (int i = 0; i < 4; ++i)
#pragma unroll
    for (int j = 0; j < 4; ++j) acc[i][j] = (floatx4){0.f,0.f,0.f,0.f};

  const int NT = 16;
  gld16(smem + aD,        Ab + aS0);
  gld16(smem + 4096 + aD, Ab + aS1);
  gld16(smem + bD,        W1T + bS0);
  gld16(smem + 4096 + bD, W1T + bS0 + 32);
  asm volatile("s_waitcnt vmcnt(1)" ::: "memory");
  __builtin_amdgcn_s_barrier();

  short8 af[2], bfr[4];
  for (int kt = 0; kt < NT; ++kt){
    const int cur = kt & 1;
    const ushort* A  = smem + cur*8192;
    const ushort* Bt = smem + 16384 + cur*4096;
#pragma unroll
    for (int n = 0; n < 4; ++n) bfr[n] = *(const short8*)&Bt[boff[n]];
#pragma unroll
    for (int m = 0; m < 2; ++m) af[m] = *(const short8*)&A[aoff[m]];
    if (kt+1 < NT){
      ushort* d = smem + (cur^1)*8192;
      const size_t ko = (size_t)(kt+1)*32;
      gld16(d + aD,        Ab + aS0 + ko);
      gld16(d + 4096 + aD, Ab + aS1 + ko);
    }
    __builtin_amdgcn_s_barrier();
    asm volatile("s_waitcnt lgkmcnt(0)" ::: "memory");
    __builtin_amdgcn_sched_barrier(0);
    __builtin_amdgcn_s_setprio(1);
#pragma unroll
    for (int m = 0; m < 2; ++m)
#pragma unroll
      for (int n = 0; n < 4; ++n)
        acc[m][n] = MFMA16(af[m], bfr[n], acc[m][n]);
    __builtin_amdgcn_s_setprio(0);
    __builtin_amdgcn_s_barrier();
#pragma unroll
    for (int m = 0; m < 2; ++m) af[m] = *(const short8*)&A[aoff[2+m]];
    if (kt+2 < NT)
      gld16(smem + cur*4096 + bD, W1T + bS0 + (size_t)(kt+2)*32);
    __builtin_amdgcn_s_barrier();
    asm volatile("s_waitcnt lgkmcnt(0)" ::: "memory");
    __builtin_amdgcn_sched_barrier(0);
    __builtin_amdgcn_s_setprio(1);
#pragma unroll
    for (int m = 0; m < 2; ++m)
#pragma unroll
      for (int n = 0; n < 4; ++n)
        acc[2+m][n] = MFMA16(af[m], bfr[n], acc[2+m][n]);
    __builtin_amdgcn_s_setprio(0);
    if (kt + 2 < NT) asm volatile("s_waitcnt vmcnt(1)" ::: "memory");
    else             asm volatile("s_waitcnt vmcnt(0)" ::: "memory");
    __builtin_amdgcn_s_barrier();
  }

#pragma unroll
  for (int m = 0; m < 4; ++m){
#pragma unroll
    for (int n = 0; n < 2; ++n){
      const int col = n0 + wc*32 + n*16 + l15;
      const float bb1 = b1[col], bb2 = b1[512 + col];
#pragma unroll
      for (int r = 0; r < 4; ++r){
        const int row = m0 + wr*64 + m*16 + quad*4 + r;
        float x1 = acc[m][n][r]     + bb1;
        float x2 = acc[m][n+2][r]   + bb2;
        float gl = 0.5f*x1*(1.0f + erff(x1*0.70710678118654752f));
        gbuf[(size_t)row*512 + col] = f2bf(gl*x2);
      }
    }
  }
}

// ---------------------------------------------------------------------------
// ff2: ff = g @ W2 (via W2T). 256x128 template, 2-bit swizzle. grid 256.
// ---------------------------------------------------------------------------
__global__ __launch_bounds__(512, 4)
void ff2(const ushort* __restrict__ gb, const ushort* __restrict__ W2T,
         ushort* __restrict__ ff)
{
  extern __shared__ __align__(16) ushort smem[];
  const int t = threadIdx.x, lane = t & 63, w = t >> 6;
  const int id = blockIdx.x;
  const int xcd = id & 7, sl = id >> 3;            // sl 0..31
  const int m0 = (xcd*8 + (sl >> 2)) * 256;
  const int n0 = (sl & 3) * 128;
  const ushort* Ab = gb  + (size_t)m0*512;
  const ushort* Bb = W2T + (size_t)n0*512;
  const int wr = w >> 1, wc = w & 1;
  const int l15 = lane & 15, quad = lane >> 4;
  const int rl = lane >> 2;
  const int cl = (lane & 3) ^ ((lane >> 3) & 3);
  const int sw = ((l15 >> 1) & 3) * 8;
  int aoff[4], boff[4];
#pragma unroll
  for (int m = 0; m < 4; ++m)
    aoff[m] = ((wr*64 + m*16 + l15)*32 + quad*8) ^ sw;
#pragma unroll
  for (int n = 0; n < 4; ++n)
    boff[n] = ((wc*64 + n*16 + l15)*32 + quad*8) ^ sw;
  const size_t aS0 = (size_t)(w*16 + rl)*512 + cl*8;
  const size_t aS1 = aS0 + (size_t)128*512;
  const size_t bS0 = (size_t)(w*16 + rl)*512 + cl*8;
  const int aD = w*512, bD = 16384 + w*512;

  floatx4 acc[4][4];
#pragma unroll
  for (int i = 0; i < 4; ++i)
#pragma unroll
    for (int j = 0; j < 4; ++j) acc[i][j] = (floatx4){0.f,0.f,0.f,0.f};

  const int NT = 16;
  gld16(smem + aD,        Ab + aS0);
  gld16(smem + 4096 + aD, Ab + aS1);
  gld16(smem + bD,        Bb + bS0);
  gld16(smem + 4096 + bD, Bb + bS0 + 32);
  asm volatile("s_waitcnt vmcnt(1)" ::: "memory");
  __builtin_amdgcn_s_barrier();

  short8 af[2], bfr[4];
  for (int kt = 0; kt < NT; ++kt){
    const int cur = kt & 1;
    const ushort* A  = smem + cur*8192;
    const ushort* Bt = smem + 16384 + cur*4096;
#pragma unroll
    for (int n = 0; n < 4; ++n) bfr[n] = *(const short8*)&Bt[boff[n]];
#pragma unroll
    for (int m = 0; m < 2; ++m) af[m] = *(const short8*)&A[aoff[m]];
    if (kt+1 < NT){
      ushort* d = smem + (cur^1)*8192;
      const size_t ko = (size_t)(kt+1)*32;
      gld16(d + aD,        Ab + aS0 + ko);
      gld16(d + 4096 + aD, Ab + aS1 + ko);
    }
    __builtin_amdgcn_s_barrier();
    asm volatile("s_waitcnt lgkmcnt(0)" ::: "memory");
    __builtin_amdgcn_sched_barrier(0);
    __builtin_amdgcn_s_setprio(1);
#pragma unroll
    for (int m = 0; m < 2; ++m)
#pragma unroll
      for (int n = 0; n < 4; ++n)
        acc[m][n] = MFMA16(af[m], bfr[n], acc[m][n]);
    __builtin_amdgcn_s_setprio(0);
    __builtin_amdgcn_s_barrier();
#pragma unroll
    for (int m = 0; m < 2; ++m) af[m] = *(const short8*)&A[aoff[2+m]];
    if (kt+2 < NT)
      gld16(smem + cur*4096 + bD, Bb + bS0 + (size_t)(kt+2)*32);
    __builtin_amdgcn_s_barrier();
    asm volatile("s_waitcnt lgkmcnt(0)" ::: "memory");
    __builtin_amdgcn_sched_barrier(0);
    __builtin_amdgcn_s_setprio(1);
#pragma unroll
    for (int m = 0; m < 2; ++m)
#pragma unroll
      for (int n = 0; n < 4; ++n)
        acc[2+m][n] = MFMA16(af[m], bfr[n], acc[2+m][n]);
    __builtin_amdgcn_s_setprio(0);
    if (kt + 2 < NT) asm volatile("s_waitcnt vmcnt(1)" ::: "memory");
    else             asm volatile("s_waitcnt vmcnt(0)" ::: "memory");
    __builtin_amdgcn_s_barrier();
  }

#pragma unroll
  for (int m = 0; m < 4; ++m){
    const int rm = m0 + wr*64 + m*16 + quad*4;
#pragma unroll
    for (int n = 0; n < 4; ++n){
      const int cn = n0 + wc*64 + n*16 + l15;
#pragma unroll
      for (int r = 0; r < 4; ++r)
        ff[(size_t)(rm + r)*512 + cn] = f2bf(acc[m][n][r]);
    }
  }
}

// ---------------------------------------------------------------------------
// res_rms2: y = h + ff + b2; out = rmsnorm(y)*n2w (fp32). One wave per row.
// ---------------------------------------------------------------------------
__global__ __launch_bounds__(256)
void res_rms2(const ushort* __restrict__ hbf, const ushort* __restrict__ ff,
              const float* __restrict__ b2, const float* __restrict__ n2w,
              float* __restrict__ out)
{
  const int wid = threadIdx.x >> 6, lane = threadIdx.x & 63;
  const size_t row = (size_t)blockIdx.x*4 + wid;
  const ushort* hr = hbf + row*512;
  const ushort* fr = ff  + row*512;
  ushort4 h0 = *(const ushort4*)&hr[lane*8];
  ushort4 h1 = *(const ushort4*)&hr[lane*8 + 4];
  ushort4 f0 = *(const ushort4*)&fr[lane*8];
  ushort4 f1 = *(const ushort4*)&fr[lane*8 + 4];
  float4 bb0 = ld4(b2 + lane*8), bb1 = ld4(b2 + lane*8 + 4);
  float y[8];
  y[0]=bf2f(h0.x)+bf2f(f0.x)+bb0.x; y[1]=bf2f(h0.y)+bf2f(f0.y)+bb0.y;
  y[2]=bf2f(h0.z)+bf2f(f0.z)+bb0.z; y[3]=bf2f(h0.w)+bf2f(f0.w)+bb0.w;
  y[4]=bf2f(h1.x)+bf2f(f1.x)+bb1.x; y[5]=bf2f(h1.y)+bf2f(f1.y)+bb1.y;
  y[6]=bf2f(h1.z)+bf2f(f1.z)+bb1.z; y[7]=bf2f(h1.w)+bf2f(f1.w)+bb1.w;
  float ss = 0.f;
#pragma unroll
  for (int e=0;e<8;++e) ss += y[e]*y[e];
#pragma unroll
  for (int s=1;s<64;s<<=1) ss += __shfl_xor(ss, s);
  const float rr = rsqrtf(ss*(1.0f/512.0f) + EPS_F);
  float4 w0 = ld4(n2w + lane*8), w1 = ld4(n2w + lane*8 + 4);
  float* orow = out + row*512;
  float4 o0, o1;
  o0.x=y[0]*rr*w0.x; o0.y=y[1]*rr*w0.y; o0.z=y[2]*rr*w0.z; o0.w=y[3]*rr*w0.w;
  o1.x=y[4]*rr*w1.x; o1.y=y[5]*rr*w1.y; o1.z=y[6]*rr*w1.z; o1.w=y[7]*rr*w1.w;
  *(float4*)(orow + lane*8)     = o0;
  *(float4*)(orow + lane*8 + 4) = o1;
}

// ---------------------------------------------------------------------------
extern "C" void kernel_launch(void* const* d_in, const int* in_sizes, int n_in,
                              void* d_out, int out_size, void* d_ws, size_t ws_size,
                              hipStream_t stream)
{
  const float* x   = (const float*)d_in[0];
  const float* q   = (const float*)d_in[1];
  const float* k   = (const float*)d_in[2];
  const float* W1  = (const float*)d_in[3];
  const float* b1  = (const float*)d_in[4];
  const float* W2  = (const float*)d_in[5];
  const float* b2  = (const float*)d_in[6];
  const float* n1w = (const float*)d_in[7];
  const float* n2w = (const float*)d_in[8];
  float* out = (float*)d_out;

  // ws (ushort units): scores 64MB | XT 16MB | Qbf 16MB | Kbf 16MB
  //                    | W1T 1MB | W2T .5MB | rowsum 64KB(float)
  ushort* scoresP = (ushort*)d_ws;
  ushort* XT  = scoresP + (size_t)8*2048*2048;
  ushort* Qbf = XT  + (size_t)8*512*2048;
  ushort* Kbf = Qbf + (size_t)8*2048*512;
  ushort* W1T = Kbf + (size_t)8*2048*512;
  ushort* W2T = W1T + (size_t)1024*512;
  float*  rowsum = (float*)(W2T + (size_t)512*512);
  ushort* attn = Qbf;      // alias: Qbf dead after qk4
  ushort* hbf  = Qbf;      // res_rms1 rewrites attn in place
  ushort* gbuf = Kbf;      // alias: Kbf dead after qk4
  ushort* ffb  = scoresP;  // alias: scores dead after pv8

  hipMemsetAsync(rowsum, 0, (size_t)8*2048*sizeof(float), stream);
  prep     <<<dim3(10432),  256, 0, stream>>>(q, k, x, W1, W2, Qbf, Kbf, XT, W1T, W2T);
  qk4      <<<dim3(1024),   512, 49152, stream>>>(Qbf, Kbf, scoresP, rowsum);
  pv8      <<<dim3(256),    512, 98304, stream>>>(scoresP, XT, rowsum, attn);
  res_rms1 <<<dim3(4096),   256, 0, stream>>>(x, n1w, hbf);
  ffn2     <<<dim3(512),    512, 49152, stream>>>(hbf, W1T, b1, gbuf);
  ff2      <<<dim3(256),    512, 49152, stream>>>(gbuf, W2T, ffb);
  res_rms2 <<<dim3(4096),   256, 0, stream>>>(hbf, ffb, b2, n2w, out);
}